// Round 1
// 725.927 us; speedup vs baseline: 1.0639x; 1.0639x over previous
//
#include <hip/hip_runtime.h>
#include <math.h>

// Problem constants (from reference)
#define NN 5000
#define NNP 5120    // padded rows for GEMM A-operand OOB staging
#define NE 50000
#define NEE 55000   // edges + self loops
#define NG 8
#define NH 4

typedef __attribute__((ext_vector_type(8))) _Float16 half8;
typedef __attribute__((ext_vector_type(4))) _Float16 half4;
typedef __attribute__((ext_vector_type(4))) float floatx4;

// ---------------- utility device functions ----------------

__device__ inline float waveSum(float v) {
    #pragma unroll
    for (int o = 32; o > 0; o >>= 1) v += __shfl_xor(v, o, 64);
    return v;
}
__device__ inline float waveMax(float v) {
    #pragma unroll
    for (int o = 32; o > 0; o >>= 1) v = fmaxf(v, __shfl_xor(v, o, 64));
    return v;
}

// async global->LDS DMA, 16B per lane; lds dest is wave-uniform base + lane*16
__device__ __forceinline__ void gload_lds16(const _Float16* g, _Float16* l) {
    __builtin_amdgcn_global_load_lds(
        (__attribute__((address_space(1))) void*)g,
        (__attribute__((address_space(3))) void*)l,
        16, 0, 0);
}

// ---------------- fp32 -> fp16 conversion ----------------

__global__ void k_cvtA(const float* __restrict__ X, _Float16* __restrict__ A0, int n) {
    int i = blockIdx.x * 256 + threadIdx.x;
    if (i >= n) return;
    A0[i] = (_Float16)X[i];
}

// W (K x M fp32) -> B0 fp16 TRANSPOSED to (M x K)
__global__ __launch_bounds__(256) void k_cvtWT(const float* __restrict__ W,
        _Float16* __restrict__ B0, int K, int M)
{
    __shared__ float tile[32][33];
    int m0 = blockIdx.x * 32, k0 = blockIdx.y * 32;
    int tx = threadIdx.x & 31, ty = threadIdx.x >> 5;
    #pragma unroll
    for (int i = 0; i < 4; ++i)
        tile[ty + 8 * i][tx] = W[(size_t)(k0 + ty + 8 * i) * M + m0 + tx];
    __syncthreads();
    #pragma unroll
    for (int i = 0; i < 4; ++i) {
        int mm = ty + 8 * i, kk = tx;
        B0[(size_t)(m0 + mm) * K + kk + k0] = (_Float16)tile[kk][mm];
    }
}

// ---------------- MFMA fp16 GEMM, dbuf global_load_lds + XOR bank swizzle ----
// C(Mrows x N) = A @ B^T + bias; A fp16 (padded rows x K), B fp16 (N x K).
// Output fp16. K-loop identical to the verified R6-R8 kernel (XOR chunk
// swizzle; 2-way LDS conflicts = free).
// NEW this round:
//  - bias comes from two pointers (cols < Nhalf -> biasL, else biasR) so the
//    Wl/Wr GEMMs sharing an A operand fuse into one dispatch (N = 2*HC).
//  - coalesced epilogue: stage the 128x128 fp16 C tile in the (now dead)
//    As/Bs LDS, then store full 256B rows as half8/lane. The old scalar
//    2B stores wrote 32B segments of 4 different rows per instruction ->
//    measured 1.9x write amplification (WRITE_SIZE 78.5MB vs 41MB ideal)
//    plus ~41MB of C-line RMW fetch.
//  - bijective XCD swizzle of the flattened block id (all grids here are
//    divisible by 8) for per-XCD L2 A/B-panel reuse.
__global__ __launch_bounds__(256) void gemm_mfma_f16(
    const _Float16* __restrict__ A0, const _Float16* __restrict__ B0,
    const float* __restrict__ biasL, const float* __restrict__ biasR,
    int Nhalf, _Float16* __restrict__ C,
    int Mrows, int K, int N)
{
    // As = smem[0 .. 8192), Bs = smem[8192 .. 16384), each [2][128*32] halfs.
    // After the K-loop the whole 16384-half (32KB) block is reused as the
    // 128x128 output tile.
    __shared__ __align__(16) _Float16 smem[2 * 2 * 128 * 32];
    _Float16* As = smem;
    _Float16* Bs = smem + 2 * 128 * 32;

    const int tid = threadIdx.x;
    const int wave = tid >> 6;
    const int lane = tid & 63;
    const int wm = (wave >> 1) * 64;
    const int wn = (wave & 1) * 64;
    const int lm = lane & 15;
    // swizzled chunk offset for fragment reads (halfs)
    const int swz = (((lane >> 4) ^ ((lane >> 1) & 3)) << 3);

    // XCD-aware bijective swizzle of the flat block id (nwg % 8 == 0 here)
    const int nwg = gridDim.x * gridDim.y;
    const int orig = blockIdx.y * gridDim.x + blockIdx.x;
    int swzId = orig;
    if ((nwg & 7) == 0) swzId = (orig & 7) * (nwg >> 3) + (orig >> 3);
    const int bx = swzId % gridDim.x;
    const int by = swzId / gridDim.x;
    const int rowBase = by * 128;
    const int colBase = bx * 128;

    floatx4 acc[4][4];
    #pragma unroll
    for (int i = 0; i < 4; ++i)
        #pragma unroll
        for (int j = 0; j < 4; ++j)
            acc[i][j] = (floatx4){0.f, 0.f, 0.f, 0.f};

    // staging: wave owns rows [w*32, w*32+32), 2 issues of 16 rows per matrix.
    // lane -> row (lane>>2), global chunk (lane&3)^((lane>>3)&3)  [the swizzle]
    const int sr = lane >> 2;
    const int scol = (((lane & 3) ^ ((lane >> 3) & 3)) << 3);
    const _Float16* gA = A0 + (size_t)(rowBase + wave * 32 + sr) * K + scol;
    const _Float16* gB = B0 + (size_t)(colBase + wave * 32 + sr) * K + scol;
    const size_t skip16 = (size_t)16 * K;
    const int lo0 = (wave * 32) * 32;
    const int lo1 = (wave * 32 + 16) * 32;

    // prologue: tile 0 -> buf 0
    gload_lds16(gA, &As[lo0]);
    gload_lds16(gA + skip16, &As[lo1]);
    gload_lds16(gB, &Bs[lo0]);
    gload_lds16(gB + skip16, &Bs[lo1]);
    __syncthreads();

    const int nk = K >> 5;
    for (int t = 0; t < nk; ++t) {
        const int p = t & 1;
        const int po = p * 128 * 32;
        if (t + 1 < nk) {          // prefetch tile t+1 into the other buffer
            const int k1 = (t + 1) << 5;
            const int qo = (p ^ 1) * 128 * 32;
            gload_lds16(gA + k1, &As[qo + lo0]);
            gload_lds16(gA + skip16 + k1, &As[qo + lo1]);
            gload_lds16(gB + k1, &Bs[qo + lo0]);
            gload_lds16(gB + skip16 + k1, &Bs[qo + lo1]);
        }
        half8 a0[4], b0[4];
        #pragma unroll
        for (int i = 0; i < 4; ++i) {
            a0[i] = *(const half8*)&As[po + (wm + i * 16 + lm) * 32 + swz];
            b0[i] = *(const half8*)&Bs[po + (wn + i * 16 + lm) * 32 + swz];
        }
        #pragma unroll
        for (int i = 0; i < 4; ++i)
            #pragma unroll
            for (int j = 0; j < 4; ++j)
                acc[i][j] = __builtin_amdgcn_mfma_f32_16x16x32_f16(a0[i], b0[j], acc[i][j], 0, 0, 0);
        __syncthreads();
    }

    // ---- coalesced epilogue ----
    // Stage the C tile (bias applied) into LDS. The final loop iteration's
    // __syncthreads guarantees all LDS reads are done and no global_load_lds
    // is in flight (no prefetch on the last iteration).
    _Float16* Ct = smem;   // [128][128] halfs
    const int cq = (lane >> 4) * 4;
    #pragma unroll
    for (int j = 0; j < 4; ++j) {
        int col = wn + j * 16 + lm;
        int gcol = colBase + col;
        float bv = (gcol < Nhalf) ? biasL[gcol] : biasR[gcol - Nhalf];
        #pragma unroll
        for (int i = 0; i < 4; ++i) {
            int row = wm + i * 16 + cq;
            #pragma unroll
            for (int r = 0; r < 4; ++r)
                Ct[(row + r) * 128 + col] = (_Float16)(acc[i][j][r] + bv);
        }
    }
    __syncthreads();
    // 256 threads store 16 rows/pass, 8 passes; each row = 16 lanes x half8
    // = 256B fully contiguous -> full-line HBM writes.
    const int r0 = tid >> 4;          // 0..15
    const int cc = (tid & 15) * 8;    // half offset within row
    #pragma unroll
    for (int ps = 0; ps < 8; ++ps) {
        int row = ps * 16 + r0;
        int grow = rowBase + row;
        if (grow < Mrows) {
            half8 v = *(const half8*)&Ct[row * 128 + cc];
            *(half8*)&C[(size_t)grow * N + colBase + cc] = v;
        }
    }
}

// ---------------- CSR build ----------------

__global__ void k_build_edges(const int* __restrict__ ei, int* __restrict__ src,
                              int* __restrict__ dst) {
    int i = blockIdx.x * 256 + threadIdx.x;
    if (i < NE) { src[i] = ei[i]; dst[i] = ei[NE + i]; }
    else if (i < NEE) { src[i] = i - NE; dst[i] = i - NE; }
}

__global__ void k_zero32(unsigned int* __restrict__ p, int n) {
    int i = blockIdx.x * 256 + threadIdx.x;
    if (i < n) p[i] = 0u;
}

__global__ void k_count(const int* __restrict__ dst, int* __restrict__ cnt) {
    int i = blockIdx.x * 256 + threadIdx.x;
    if (i < NEE) atomicAdd(&cnt[dst[i]], 1);
}

__global__ __launch_bounds__(256) void k_scan(const int* __restrict__ cnt,
                                              int* __restrict__ off, int* __restrict__ cur) {
    __shared__ int partial[256];
    __shared__ int ppre[257];
    int t = threadIdx.x;
    const int chunk = (NN + 255) / 256;
    int lo = t * chunk, hi = min(NN, (t + 1) * chunk);
    int s = 0;
    for (int i = lo; i < hi; ++i) s += cnt[i];
    partial[t] = s;
    __syncthreads();
    if (t == 0) {
        int acc = 0;
        for (int i = 0; i < 256; ++i) { ppre[i] = acc; acc += partial[i]; }
        ppre[256] = acc;
    }
    __syncthreads();
    int acc = ppre[t];
    for (int i = lo; i < hi; ++i) { off[i] = acc; cur[i] = acc; acc += cnt[i]; }
    if (t == 0) off[NN] = ppre[256];
}

__global__ void k_fill(const int* __restrict__ src, const int* __restrict__ dst,
                       int* __restrict__ cur, int* __restrict__ slist) {
    int e = blockIdx.x * 256 + threadIdx.x;
    if (e < NEE) { int p = atomicAdd(&cur[dst[e]], 1); slist[p] = src[e]; }
}

// ---------------- fused GATv2 edge pipeline (fp16 activations) -------------
// xlr is the fused GEMM output: row n = [xl(n) | xr(n)], stride LD = 2*NH*C.
// NEW this round: half8 gathers (16B/lane) for C>=512, and a one-deep
// register prefetch of the next source row so the serial online-softmax
// chain overlaps the ~L2/L3 gather latency of the following edge.
template<int C>
__global__ __launch_bounds__(256) void k_gat_fused(
    const _Float16* __restrict__ xlr, const float* __restrict__ att,
    const int* __restrict__ eoff, const int* __restrict__ slist,
    const float* __restrict__ bias, _Float16* __restrict__ out)
{
    constexpr int LD = 2 * NH * C;          // fused GEMM row stride (halfs)
    constexpr int CH = (C >= 512) ? 8 : 4;  // halfs per load per lane
    constexpr int NC = C / (64 * CH);       // chunks per head-row (1024:2, else 1)
    constexpr int PL = NC * CH;             // elems per lane (16 / 8 / 4)
    __shared__ float red[NH * C];
    const int n = blockIdx.x;
    const int h = threadIdx.x >> 6;
    const int lane = threadIdx.x & 63;

    float xrv[PL], attv[PL], acc[PL];
    {
        const _Float16* xrrow = xlr + (size_t)n * LD + NH * C + h * C + lane * CH;
        const float* ah = att + h * C + lane * CH;
        #pragma unroll
        for (int c = 0; c < NC; ++c) {
            if constexpr (CH == 8) {
                half8 hv = *(const half8*)(xrrow + c * 64 * CH);
                #pragma unroll
                for (int e = 0; e < 8; ++e) xrv[c * 8 + e] = (float)hv[e];
            } else {
                half4 hv = *(const half4*)(xrrow + c * 64 * CH);
                #pragma unroll
                for (int e = 0; e < 4; ++e) xrv[c * 4 + e] = (float)hv[e];
            }
            #pragma unroll
            for (int e = 0; e < CH; e += 4) {
                float4 a4 = *(const float4*)(ah + c * 64 * CH + e);
                attv[c * CH + e + 0] = a4.x; attv[c * CH + e + 1] = a4.y;
                attv[c * CH + e + 2] = a4.z; attv[c * CH + e + 3] = a4.w;
            }
        }
        #pragma unroll
        for (int e = 0; e < PL; ++e) acc[e] = 0.f;
    }

    float m = -INFINITY, den = 0.f;
    const int start = eoff[n], end = eoff[n + 1];

    _Float16 bufA[PL], bufB[PL];
    auto ldrow = [&](int s, _Float16* buf) {
        const _Float16* p = xlr + (size_t)s * LD + h * C + lane * CH;
        #pragma unroll
        for (int c = 0; c < NC; ++c) {
            if constexpr (CH == 8)
                *(half8*)&buf[c * 8] = *(const half8*)(p + c * 64 * CH);
            else
                *(half4*)&buf[c * 4] = *(const half4*)(p + c * 64 * CH);
        }
    };

    if (start < end) ldrow(slist[start], bufA);
    for (int j = start; j < end; ++j) {
        if (j + 1 < end) ldrow(slist[j + 1], bufB);   // prefetch next src row
        float xv[PL];
        float ps = 0.f;
        #pragma unroll
        for (int e = 0; e < PL; ++e) {
            xv[e] = (float)bufA[e];
            float v = xv[e] + xrv[e];
            v = v > 0.f ? v : 0.2f * v;
            ps = fmaf(v, attv[e], ps);
        }
        ps = waveSum(ps);
        float m_new = fmaxf(m, ps);
        float scale = expf(m - m_new);
        float ex = expf(ps - m_new);
        den = den * scale + ex;
        m = m_new;
        #pragma unroll
        for (int e = 0; e < PL; ++e)
            acc[e] = fmaf(ex, xv[e], acc[e] * scale);
        #pragma unroll
        for (int e = 0; e < PL; ++e) bufA[e] = bufB[e];
    }

    float inv = 1.f / (den + 1e-16f);
    #pragma unroll
    for (int c = 0; c < NC; ++c) {
        int off = h * C + c * 64 * CH + lane * CH;
        #pragma unroll
        for (int e = 0; e < CH; e += 4) {
            float4 r;
            r.x = acc[c * CH + e + 0] * inv;
            r.y = acc[c * CH + e + 1] * inv;
            r.z = acc[c * CH + e + 2] * inv;
            r.w = acc[c * CH + e + 3] * inv;
            *(float4*)&red[off + e] = r;
        }
    }
    __syncthreads();

    int t = threadIdx.x;
    for (int c4 = t; c4 < C / 4; c4 += 256) {
        int c = c4 * 4;
        float4 r0 = *(const float4*)&red[0 * C + c];
        float4 r1 = *(const float4*)&red[1 * C + c];
        float4 r2 = *(const float4*)&red[2 * C + c];
        float4 r3 = *(const float4*)&red[3 * C + c];
        float4 bv = *(const float4*)(bias + c);
        half4 o;
        o[0] = (_Float16)fmaxf((r0.x + r1.x + r2.x + r3.x) * 0.25f + bv.x, 0.f);
        o[1] = (_Float16)fmaxf((r0.y + r1.y + r2.y + r3.y) * 0.25f + bv.y, 0.f);
        o[2] = (_Float16)fmaxf((r0.z + r1.z + r2.z + r3.z) * 0.25f + bv.z, 0.f);
        o[3] = (_Float16)fmaxf((r0.w + r1.w + r2.w + r3.w) * 0.25f + bv.w, 0.f);
        *(half4*)(out + (size_t)n * C + c) = o;
    }
}

// ---------------- gate + pool + MLP ----------------

__global__ __launch_bounds__(128) void k_gate(
    const _Float16* __restrict__ x, const float* __restrict__ Wg0,
    const float* __restrict__ bg0, const float* __restrict__ Wg1,
    const float* __restrict__ bg1, float* __restrict__ g)
{
    int n = blockIdx.x;
    int t = threadIdx.x;
    __shared__ float xs[256];
    __shared__ float wsum[2];
    const _Float16* xp = x + (size_t)n * 256;
    xs[t] = (float)xp[t]; xs[t + 128] = (float)xp[t + 128];
    __syncthreads();
    float acc = bg0[t];
    for (int k = 0; k < 256; ++k) acc = fmaf(xs[k], Wg0[k * 128 + t], acc);
    acc = acc > 0.f ? acc : 0.f;
    float prod = acc * Wg1[t];
    prod = waveSum(prod);
    if ((t & 63) == 0) wsum[t >> 6] = prod;
    __syncthreads();
    if (t == 0) g[n] = wsum[0] + wsum[1] + bg1[0];
}

__global__ void k_group_bounds(const int* __restrict__ batch, int* __restrict__ gstart,
                               int* __restrict__ gend) {
    int n = blockIdx.x * 256 + threadIdx.x;
    if (n >= NN) return;
    int b = batch[n];
    if (n == 0 || batch[n - 1] != b) gstart[b] = n;
    if (n == NN - 1 || batch[n + 1] != b) gend[b] = n + 1;
}

// per-group softmax stats: m[g], invden[g]
__global__ __launch_bounds__(256) void k_pool_stats(
    const float* __restrict__ g, const int* __restrict__ gstart,
    const int* __restrict__ gend, float* __restrict__ mOut,
    float* __restrict__ invdenOut)
{
    int gi = blockIdx.x;
    int t = threadIdx.x;
    int s0 = gstart[gi], e0 = gend[gi];
    __shared__ float red[4];
    float mx = -1e30f;
    for (int n = s0 + t; n < e0; n += 256) mx = fmaxf(mx, g[n]);
    float wm = waveMax(mx);
    if ((t & 63) == 0) red[t >> 6] = wm;
    __syncthreads();
    float m = fmaxf(fmaxf(red[0], red[1]), fmaxf(red[2], red[3]));
    __syncthreads();
    float sm = 0.f;
    for (int n = s0 + t; n < e0; n += 256) sm += expf(g[n] - m);
    sm = waveSum(sm);
    if ((t & 63) == 0) red[t >> 6] = sm;
    __syncthreads();
    if (t == 0) {
        float den = red[0] + red[1] + red[2] + red[3] + 1e-16f;
        mOut[gi] = m;
        invdenOut[gi] = 1.f / den;
    }
}

#define PCH 16
__global__ __launch_bounds__(256) void k_pool_acc(
    const _Float16* __restrict__ x, const float* __restrict__ g,
    const int* __restrict__ batch, const float* __restrict__ m,
    const float* __restrict__ invden, float* __restrict__ hpool)
{
    int base = blockIdx.x * PCH;
    int t = threadIdx.x;
    float acc = 0.f;
    int cur = -1;
    for (int i = 0; i < PCH; ++i) {
        int n = base + i;
        if (n >= NN) break;
        int b = batch[n];
        if (b != cur) {
            if (cur >= 0) atomicAdd(&hpool[cur * 256 + t], acc);
            cur = b; acc = 0.f;
        }
        float w = expf(g[n] - m[b]) * invden[b];
        acc = fmaf(w, (float)x[(size_t)n * 256 + t], acc);
    }
    if (cur >= 0) atomicAdd(&hpool[cur * 256 + t], acc);
}

__global__ __launch_bounds__(256) void k_mlp(
    const float* __restrict__ hpool,
    const float* __restrict__ Wm0, const float* __restrict__ bm0,
    const float* __restrict__ Wm1, const float* __restrict__ bm1,
    const float* __restrict__ Wm2, const float* __restrict__ bm2,
    const float* __restrict__ Wm3, const float* __restrict__ bm3,
    const float* __restrict__ Wm4, const float* __restrict__ bm4,
    float* __restrict__ out)
{
    __shared__ float bufA[8 * 256];
    __shared__ float bufB[8 * 128];
    int t = threadIdx.x;
    for (int i = t; i < 8 * 256; i += 256) bufA[i] = hpool[i];
    __syncthreads();
    for (int i = t; i < 8 * 128; i += 256) {
        int r = i >> 7, c = i & 127;
        float acc = bm0[c];
        for (int k = 0; k < 256; ++k) acc = fmaf(bufA[r * 256 + k], Wm0[k * 128 + c], acc);
        bufB[i] = fmaxf(acc, 0.f);
    }
    __syncthreads();
    for (int i = t; i < 8 * 64; i += 256) {
        int r = i >> 6, c = i & 63;
        float acc = bm1[c];
        for (int k = 0; k < 128; ++k) acc = fmaf(bufB[r * 128 + k], Wm1[k * 64 + c], acc);
        bufA[i] = fmaxf(acc, 0.f);
    }
    __syncthreads();
    for (int i = t; i < 8 * 32; i += 256) {
        int r = i >> 5, c = i & 31;
        float acc = bm2[c];
        for (int k = 0; k < 64; ++k) acc = fmaf(bufA[r * 64 + k], Wm2[k * 32 + c], acc);
        bufB[i] = fmaxf(acc, 0.f);
    }
    __syncthreads();
    for (int i = t; i < 8 * 16; i += 256) {
        int r = i >> 4, c = i & 15;
        float acc = bm3[c];
        for (int k = 0; k < 32; ++k) acc = fmaf(bufB[r * 32 + k], Wm3[k * 16 + c], acc);
        bufA[i] = fmaxf(acc, 0.f);
    }
    __syncthreads();
    if (t < 8) {
        float acc = bm4[0];
        for (int k = 0; k < 16; ++k) acc = fmaf(bufA[t * 16 + k], Wm4[k], acc);
        out[t] = acc;
    }
}

// ---------------- host orchestration ----------------

static void run_gat_layer(const _Float16* ain, int K, int C,
                          const float* Wl, const float* bl,
                          const float* Wr, const float* br,
                          const float* att, const float* bias,
                          _Float16* wb0, _Float16* xlr,
                          const int* eoff, const int* slist,
                          _Float16* xout, hipStream_t stream)
{
    int HC = NH * C;
    dim3 tgrid(HC / 32, K / 32);
    k_cvtWT<<<tgrid, 256, 0, stream>>>(Wl, wb0, K, HC);
    k_cvtWT<<<tgrid, 256, 0, stream>>>(Wr, wb0 + (size_t)HC * K, K, HC);
    // fused Wl/Wr GEMM: N = 2*HC, output row n = [xl(n) | xr(n)]
    dim3 ggrid(2 * HC / 128, NNP / 128);
    gemm_mfma_f16<<<ggrid, 256, 0, stream>>>(ain, wb0, bl, br, HC, xlr, NN, K, 2 * HC);

    if (C == 1024)
        k_gat_fused<1024><<<NN, 256, 0, stream>>>(xlr, att, eoff, slist, bias, xout);
    else if (C == 512)
        k_gat_fused<512><<<NN, 256, 0, stream>>>(xlr, att, eoff, slist, bias, xout);
    else
        k_gat_fused<256><<<NN, 256, 0, stream>>>(xlr, att, eoff, slist, bias, xout);
}

extern "C" void kernel_launch(void* const* d_in, const int* in_sizes, int n_in,
                              void* d_out, int out_size, void* d_ws, size_t ws_size,
                              hipStream_t stream) {
    const float* x      = (const float*)d_in[0];
    const int* ei       = (const int*)d_in[1];
    const int* batch    = (const int*)d_in[2];
    const float* Wl1 = (const float*)d_in[3];  const float* bl1 = (const float*)d_in[4];
    const float* Wr1 = (const float*)d_in[5];  const float* br1 = (const float*)d_in[6];
    const float* att1= (const float*)d_in[7];  const float* b1  = (const float*)d_in[8];
    const float* Wl2 = (const float*)d_in[9];  const float* bl2 = (const float*)d_in[10];
    const float* Wr2 = (const float*)d_in[11]; const float* br2 = (const float*)d_in[12];
    const float* att2= (const float*)d_in[13]; const float* b2  = (const float*)d_in[14];
    const float* Wl3 = (const float*)d_in[15]; const float* bl3 = (const float*)d_in[16];
    const float* Wr3 = (const float*)d_in[17]; const float* br3 = (const float*)d_in[18];
    const float* att3= (const float*)d_in[19]; const float* b3  = (const float*)d_in[20];
    const float* Wm0 = (const float*)d_in[21]; const float* bm0 = (const float*)d_in[22];
    const float* Wm1 = (const float*)d_in[23]; const float* bm1 = (const float*)d_in[24];
    const float* Wm2 = (const float*)d_in[25]; const float* bm2 = (const float*)d_in[26];
    const float* Wm3 = (const float*)d_in[27]; const float* bm3 = (const float*)d_in[28];
    const float* Wm4 = (const float*)d_in[29]; const float* bm4 = (const float*)d_in[30];
    const float* Wg0 = (const float*)d_in[31]; const float* bg0 = (const float*)d_in[32];
    const float* Wg1 = (const float*)d_in[33]; const float* bg1 = (const float*)d_in[34];
    float* out = (float*)d_out;

    // workspace carve (float units = 4B); fp16 buffers 16B-aligned, padded rows
    float* ws = (float*)d_ws;
    size_t o = 0;
    _Float16* xlr = (_Float16*)(ws + o); o += (size_t)NNP * 8192 / 2;  // fused [xl|xr], layer1 sized
    _Float16* x1  = (_Float16*)(ws + o); o += (size_t)NNP * 1024 / 2;
    _Float16* x2  = (_Float16*)(ws + o); o += (size_t)NNP * 512 / 2;
    _Float16* x3  = (_Float16*)(ws + o); o += (size_t)NNP * 256 / 2;
    _Float16* a0p = (_Float16*)(ws + o); o += (size_t)NNP * 1536 / 2;
    _Float16* wb0 = (_Float16*)(ws + o); o += (size_t)8192 * 1536 / 2; // [WlT | WrT], layer1 sized
    int* srcA    = (int*)(ws + o); o += NEE;
    int* dstA    = (int*)(ws + o); o += NEE;
    int* cnt     = (int*)(ws + o); o += NN;
    int* eoff    = (int*)(ws + o); o += NN + 1;
    int* cur     = (int*)(ws + o); o += NN;
    int* slist   = (int*)(ws + o); o += NEE;
    float* g     = ws + o; o += NN;
    int* gstart  = (int*)(ws + o); o += NG;
    int* gend    = (int*)(ws + o); o += NG;
    float* gm    = ws + o; o += NG;
    float* ginv  = ws + o; o += NG;
    float* hpool = ws + o; o += NG * 256;

    // build CSR by dst (slist holds src node ids)
    int ebB = (NEE + 255) / 256;
    k_build_edges<<<ebB, 256, 0, stream>>>(ei, srcA, dstA);
    k_zero32<<<(NN + 255) / 256, 256, 0, stream>>>((unsigned int*)cnt, NN);
    k_count<<<ebB, 256, 0, stream>>>(dstA, cnt);
    k_scan<<<1, 256, 0, stream>>>(cnt, eoff, cur);
    k_fill<<<ebB, 256, 0, stream>>>(srcA, dstA, cur, slist);

    // layer-1 input -> fp16 (only conversion needed; later layers emit fp16)
    int nA = NN * 1536;
    k_cvtA<<<(nA + 255) / 256, 256, 0, stream>>>(x, a0p, nA);

    // three GATv2 layers
    run_gat_layer(a0p, 1536, 1024, Wl1, bl1, Wr1, br1, att1, b1,
                  wb0, xlr, eoff, slist, x1, stream);
    run_gat_layer(x1,  1024, 512,  Wl2, bl2, Wr2, br2, att2, b2,
                  wb0, xlr, eoff, slist, x2, stream);
    run_gat_layer(x2,  512,  256,  Wl3, bl3, Wr3, br3, att3, b3,
                  wb0, xlr, eoff, slist, x3, stream);

    // gate + pool + MLP
    k_gate<<<NN, 128, 0, stream>>>(x3, Wg0, bg0, Wg1, bg1, g);
    k_zero32<<<1, 64, 0, stream>>>((unsigned int*)gstart, 2 * NG);
    k_group_bounds<<<(NN + 255) / 256, 256, 0, stream>>>(batch, gstart, gend);
    k_pool_stats<<<NG, 256, 0, stream>>>(g, gstart, gend, gm, ginv);
    k_zero32<<<(NG * 256 + 255) / 256, 256, 0, stream>>>((unsigned int*)hpool, NG * 256);
    k_pool_acc<<<(NN + PCH - 1) / PCH, 256, 0, stream>>>(x3, g, batch, gm, ginv, hpool);
    k_mlp<<<1, 256, 0, stream>>>(hpool, Wm0, bm0, Wm1, bm1, Wm2, bm2,
                                 Wm3, bm3, Wm4, bm4, out);
}

// Round 2
// 699.680 us; speedup vs baseline: 1.1038x; 1.0375x over previous
//
#include <hip/hip_runtime.h>
#include <math.h>

// Problem constants (from reference)
#define NN 5000
#define NNP 5120    // padded rows for GEMM A-operand OOB staging
#define NE 50000
#define NEE 55000   // edges + self loops
#define NG 8
#define NH 4

typedef __attribute__((ext_vector_type(8))) _Float16 half8;
typedef __attribute__((ext_vector_type(4))) _Float16 half4;
typedef __attribute__((ext_vector_type(4))) float floatx4;

// ---------------- utility device functions ----------------

__device__ inline float waveSum(float v) {
    #pragma unroll
    for (int o = 32; o > 0; o >>= 1) v += __shfl_xor(v, o, 64);
    return v;
}
__device__ inline float waveMax(float v) {
    #pragma unroll
    for (int o = 32; o > 0; o >>= 1) v = fmaxf(v, __shfl_xor(v, o, 64));
    return v;
}

// async global->LDS DMA, 16B per lane; lds dest is wave-uniform base + lane*16
__device__ __forceinline__ void gload_lds16(const _Float16* g, _Float16* l) {
    __builtin_amdgcn_global_load_lds(
        (__attribute__((address_space(1))) void*)g,
        (__attribute__((address_space(3))) void*)l,
        16, 0, 0);
}

// ---------------- fp32 -> fp16 conversion ----------------

__global__ void k_cvtA(const float* __restrict__ X, _Float16* __restrict__ A0, int n) {
    int i = blockIdx.x * 256 + threadIdx.x;
    if (i >= n) return;
    A0[i] = (_Float16)X[i];
}

// W (K x M fp32) -> B0 fp16 TRANSPOSED to (M x K)
__global__ __launch_bounds__(256) void k_cvtWT(const float* __restrict__ W,
        _Float16* __restrict__ B0, int K, int M)
{
    __shared__ float tile[32][33];
    int m0 = blockIdx.x * 32, k0 = blockIdx.y * 32;
    int tx = threadIdx.x & 31, ty = threadIdx.x >> 5;
    #pragma unroll
    for (int i = 0; i < 4; ++i)
        tile[ty + 8 * i][tx] = W[(size_t)(k0 + ty + 8 * i) * M + m0 + tx];
    __syncthreads();
    #pragma unroll
    for (int i = 0; i < 4; ++i) {
        int mm = ty + 8 * i, kk = tx;
        B0[(size_t)(m0 + mm) * K + kk + k0] = (_Float16)tile[kk][mm];
    }
}

// ---------------- MFMA fp16 GEMM, dbuf global_load_lds + XOR bank swizzle ----
// C(Mrows x N) = A @ B^T + bias; A fp16 (padded rows x K), B fp16 (N x K).
// Fused Wl/Wr: bias from biasL (cols < Nhalf) or biasR, N = 2*HC.
// Block order is NATURAL: with gridDim.x % 8 == 0 the HW round-robin gives
// XCD x the column stripe c % 8 == x (8 B-panels = 3.1MB, L2-resident across
// all row panels). R1's explicit "XCD swizzle" handed each XCD row-major
// sweeps instead -> B slab 25MB >> 4MB L2 -> FETCH 409MB (measured, vs
// 148MB natural). Reverted.
// Coalesced epilogue (R1, kept): stage C tile in the dead As/Bs LDS, store
// 256B rows. WRITE_SIZE measured exactly ideal (80MB). New: XOR-swizzle the
// 16-half chunk by (row>>2)&7 so the 4 lane-groups of the staging writes hit
// 4 distinct bank quadrants (was 8-way -> 1.31M conflict cycles).
__global__ __launch_bounds__(256) void gemm_mfma_f16(
    const _Float16* __restrict__ A0, const _Float16* __restrict__ B0,
    const float* __restrict__ biasL, const float* __restrict__ biasR,
    int Nhalf, _Float16* __restrict__ C,
    int Mrows, int K, int N)
{
    // As = smem[0 .. 8192), Bs = smem[8192 .. 16384), each [2][128*32] halfs.
    // After the K-loop the whole 16384-half (32KB) block is reused as the
    // 128x128 output tile.
    __shared__ __align__(16) _Float16 smem[2 * 2 * 128 * 32];
    _Float16* As = smem;
    _Float16* Bs = smem + 2 * 128 * 32;

    const int tid = threadIdx.x;
    const int wave = tid >> 6;
    const int lane = tid & 63;
    const int wm = (wave >> 1) * 64;
    const int wn = (wave & 1) * 64;
    const int lm = lane & 15;
    // swizzled chunk offset for fragment reads (halfs)
    const int swz = (((lane >> 4) ^ ((lane >> 1) & 3)) << 3);

    const int rowBase = blockIdx.y * 128;
    const int colBase = blockIdx.x * 128;

    floatx4 acc[4][4];
    #pragma unroll
    for (int i = 0; i < 4; ++i)
        #pragma unroll
        for (int j = 0; j < 4; ++j)
            acc[i][j] = (floatx4){0.f, 0.f, 0.f, 0.f};

    // staging: wave owns rows [w*32, w*32+32), 2 issues of 16 rows per matrix.
    // lane -> row (lane>>2), global chunk (lane&3)^((lane>>3)&3)  [the swizzle]
    const int sr = lane >> 2;
    const int scol = (((lane & 3) ^ ((lane >> 3) & 3)) << 3);
    const _Float16* gA = A0 + (size_t)(rowBase + wave * 32 + sr) * K + scol;
    const _Float16* gB = B0 + (size_t)(colBase + wave * 32 + sr) * K + scol;
    const size_t skip16 = (size_t)16 * K;
    const int lo0 = (wave * 32) * 32;
    const int lo1 = (wave * 32 + 16) * 32;

    // prologue: tile 0 -> buf 0
    gload_lds16(gA, &As[lo0]);
    gload_lds16(gA + skip16, &As[lo1]);
    gload_lds16(gB, &Bs[lo0]);
    gload_lds16(gB + skip16, &Bs[lo1]);
    __syncthreads();

    const int nk = K >> 5;
    for (int t = 0; t < nk; ++t) {
        const int p = t & 1;
        const int po = p * 128 * 32;
        if (t + 1 < nk) {          // prefetch tile t+1 into the other buffer
            const int k1 = (t + 1) << 5;
            const int qo = (p ^ 1) * 128 * 32;
            gload_lds16(gA + k1, &As[qo + lo0]);
            gload_lds16(gA + skip16 + k1, &As[qo + lo1]);
            gload_lds16(gB + k1, &Bs[qo + lo0]);
            gload_lds16(gB + skip16 + k1, &Bs[qo + lo1]);
        }
        half8 a0[4], b0[4];
        #pragma unroll
        for (int i = 0; i < 4; ++i) {
            a0[i] = *(const half8*)&As[po + (wm + i * 16 + lm) * 32 + swz];
            b0[i] = *(const half8*)&Bs[po + (wn + i * 16 + lm) * 32 + swz];
        }
        #pragma unroll
        for (int i = 0; i < 4; ++i)
            #pragma unroll
            for (int j = 0; j < 4; ++j)
                acc[i][j] = __builtin_amdgcn_mfma_f32_16x16x32_f16(a0[i], b0[j], acc[i][j], 0, 0, 0);
        __syncthreads();
    }

    // ---- coalesced epilogue ----
    // Stage the C tile (bias applied) into LDS. The final loop iteration's
    // __syncthreads guarantees all LDS reads are done and no global_load_lds
    // is in flight (no prefetch on the last iteration).
    // Bank swizzle: half-index col chunk (16 halfs = 32B) XORed with
    // (row>>2)&7 -> the 4 lane groups (rows +0/+4/+8/+12) write 4 distinct
    // bank quadrants; reads stay full-row (bijection per row).
    _Float16* Ct = smem;   // [128][128] halfs, chunk-swizzled
    const int cq = (lane >> 4) * 4;
    #pragma unroll
    for (int j = 0; j < 4; ++j) {
        int col = wn + j * 16 + lm;
        int gcol = colBase + col;
        float bv = (gcol < Nhalf) ? biasL[gcol] : biasR[gcol - Nhalf];
        #pragma unroll
        for (int i = 0; i < 4; ++i) {
            int row = wm + i * 16 + cq;
            #pragma unroll
            for (int r = 0; r < 4; ++r) {
                int rr = row + r;
                Ct[rr * 128 + (col ^ (((rr >> 2) & 7) << 4))] = (_Float16)(acc[i][j][r] + bv);
            }
        }
    }
    __syncthreads();
    // 256 threads store 16 rows/pass, 8 passes; each row = 16 lanes x half8
    // = 256B fully contiguous -> full-line HBM writes.
    const int r0 = tid >> 4;          // 0..15
    const int cc = (tid & 15) * 8;    // half offset within row
    #pragma unroll
    for (int ps = 0; ps < 8; ++ps) {
        int row = ps * 16 + r0;
        int grow = rowBase + row;
        if (grow < Mrows) {
            half8 v = *(const half8*)&Ct[row * 128 + (cc ^ (((row >> 2) & 7) << 4))];
            *(half8*)&C[(size_t)grow * N + colBase + cc] = v;
        }
    }
}

// ---------------- CSR build ----------------

__global__ void k_build_edges(const int* __restrict__ ei, int* __restrict__ src,
                              int* __restrict__ dst) {
    int i = blockIdx.x * 256 + threadIdx.x;
    if (i < NE) { src[i] = ei[i]; dst[i] = ei[NE + i]; }
    else if (i < NEE) { src[i] = i - NE; dst[i] = i - NE; }
}

__global__ void k_zero32(unsigned int* __restrict__ p, int n) {
    int i = blockIdx.x * 256 + threadIdx.x;
    if (i < n) p[i] = 0u;
}

__global__ void k_count(const int* __restrict__ dst, int* __restrict__ cnt) {
    int i = blockIdx.x * 256 + threadIdx.x;
    if (i < NEE) atomicAdd(&cnt[dst[i]], 1);
}

__global__ __launch_bounds__(256) void k_scan(const int* __restrict__ cnt,
                                              int* __restrict__ off, int* __restrict__ cur) {
    __shared__ int partial[256];
    __shared__ int ppre[257];
    int t = threadIdx.x;
    const int chunk = (NN + 255) / 256;
    int lo = t * chunk, hi = min(NN, (t + 1) * chunk);
    int s = 0;
    for (int i = lo; i < hi; ++i) s += cnt[i];
    partial[t] = s;
    __syncthreads();
    if (t == 0) {
        int acc = 0;
        for (int i = 0; i < 256; ++i) { ppre[i] = acc; acc += partial[i]; }
        ppre[256] = acc;
    }
    __syncthreads();
    int acc = ppre[t];
    for (int i = lo; i < hi; ++i) { off[i] = acc; cur[i] = acc; acc += cnt[i]; }
    if (t == 0) off[NN] = ppre[256];
}

__global__ void k_fill(const int* __restrict__ src, const int* __restrict__ dst,
                       int* __restrict__ cur, int* __restrict__ slist) {
    int e = blockIdx.x * 256 + threadIdx.x;
    if (e < NEE) { int p = atomicAdd(&cur[dst[e]], 1); slist[p] = src[e]; }
}

// ---------------- fused GATv2 edge pipeline (fp16 activations) -------------
// xlr is the fused GEMM output: row n = [xl(n) | xr(n)], stride LD = 2*NH*C.
// half8 gathers (16B/lane) for C>=512, and a one-deep register prefetch of
// the next source row so the serial online-softmax chain overlaps the
// ~L2/L3 gather latency of the following edge.
template<int C>
__global__ __launch_bounds__(256) void k_gat_fused(
    const _Float16* __restrict__ xlr, const float* __restrict__ att,
    const int* __restrict__ eoff, const int* __restrict__ slist,
    const float* __restrict__ bias, _Float16* __restrict__ out)
{
    constexpr int LD = 2 * NH * C;          // fused GEMM row stride (halfs)
    constexpr int CH = (C >= 512) ? 8 : 4;  // halfs per load per lane
    constexpr int NC = C / (64 * CH);       // chunks per head-row (1024:2, else 1)
    constexpr int PL = NC * CH;             // elems per lane (16 / 8 / 4)
    __shared__ float red[NH * C];
    const int n = blockIdx.x;
    const int h = threadIdx.x >> 6;
    const int lane = threadIdx.x & 63;

    float xrv[PL], attv[PL], acc[PL];
    {
        const _Float16* xrrow = xlr + (size_t)n * LD + NH * C + h * C + lane * CH;
        const float* ah = att + h * C + lane * CH;
        #pragma unroll
        for (int c = 0; c < NC; ++c) {
            if constexpr (CH == 8) {
                half8 hv = *(const half8*)(xrrow + c * 64 * CH);
                #pragma unroll
                for (int e = 0; e < 8; ++e) xrv[c * 8 + e] = (float)hv[e];
            } else {
                half4 hv = *(const half4*)(xrrow + c * 64 * CH);
                #pragma unroll
                for (int e = 0; e < 4; ++e) xrv[c * 4 + e] = (float)hv[e];
            }
            #pragma unroll
            for (int e = 0; e < CH; e += 4) {
                float4 a4 = *(const float4*)(ah + c * 64 * CH + e);
                attv[c * CH + e + 0] = a4.x; attv[c * CH + e + 1] = a4.y;
                attv[c * CH + e + 2] = a4.z; attv[c * CH + e + 3] = a4.w;
            }
        }
        #pragma unroll
        for (int e = 0; e < PL; ++e) acc[e] = 0.f;
    }

    float m = -INFINITY, den = 0.f;
    const int start = eoff[n], end = eoff[n + 1];

    _Float16 bufA[PL], bufB[PL];
    auto ldrow = [&](int s, _Float16* buf) {
        const _Float16* p = xlr + (size_t)s * LD + h * C + lane * CH;
        #pragma unroll
        for (int c = 0; c < NC; ++c) {
            if constexpr (CH == 8)
                *(half8*)&buf[c * 8] = *(const half8*)(p + c * 64 * CH);
            else
                *(half4*)&buf[c * 4] = *(const half4*)(p + c * 64 * CH);
        }
    };

    if (start < end) ldrow(slist[start], bufA);
    for (int j = start; j < end; ++j) {
        if (j + 1 < end) ldrow(slist[j + 1], bufB);   // prefetch next src row
        float xv[PL];
        float ps = 0.f;
        #pragma unroll
        for (int e = 0; e < PL; ++e) {
            xv[e] = (float)bufA[e];
            float v = xv[e] + xrv[e];
            v = v > 0.f ? v : 0.2f * v;
            ps = fmaf(v, attv[e], ps);
        }
        ps = waveSum(ps);
        float m_new = fmaxf(m, ps);
        float scale = expf(m - m_new);
        float ex = expf(ps - m_new);
        den = den * scale + ex;
        m = m_new;
        #pragma unroll
        for (int e = 0; e < PL; ++e)
            acc[e] = fmaf(ex, xv[e], acc[e] * scale);
        #pragma unroll
        for (int e = 0; e < PL; ++e) bufA[e] = bufB[e];
    }

    float inv = 1.f / (den + 1e-16f);
    #pragma unroll
    for (int c = 0; c < NC; ++c) {
        int off = h * C + c * 64 * CH + lane * CH;
        #pragma unroll
        for (int e = 0; e < CH; e += 4) {
            float4 r;
            r.x = acc[c * CH + e + 0] * inv;
            r.y = acc[c * CH + e + 1] * inv;
            r.z = acc[c * CH + e + 2] * inv;
            r.w = acc[c * CH + e + 3] * inv;
            *(float4*)&red[off + e] = r;
        }
    }
    __syncthreads();

    int t = threadIdx.x;
    for (int c4 = t; c4 < C / 4; c4 += 256) {
        int c = c4 * 4;
        float4 r0 = *(const float4*)&red[0 * C + c];
        float4 r1 = *(const float4*)&red[1 * C + c];
        float4 r2 = *(const float4*)&red[2 * C + c];
        float4 r3 = *(const float4*)&red[3 * C + c];
        float4 bv = *(const float4*)(bias + c);
        half4 o;
        o[0] = (_Float16)fmaxf((r0.x + r1.x + r2.x + r3.x) * 0.25f + bv.x, 0.f);
        o[1] = (_Float16)fmaxf((r0.y + r1.y + r2.y + r3.y) * 0.25f + bv.y, 0.f);
        o[2] = (_Float16)fmaxf((r0.z + r1.z + r2.z + r3.z) * 0.25f + bv.z, 0.f);
        o[3] = (_Float16)fmaxf((r0.w + r1.w + r2.w + r3.w) * 0.25f + bv.w, 0.f);
        *(half4*)(out + (size_t)n * C + c) = o;
    }
}

// ---------------- gate + pool + MLP ----------------

__global__ __launch_bounds__(128) void k_gate(
    const _Float16* __restrict__ x, const float* __restrict__ Wg0,
    const float* __restrict__ bg0, const float* __restrict__ Wg1,
    const float* __restrict__ bg1, float* __restrict__ g)
{
    int n = blockIdx.x;
    int t = threadIdx.x;
    __shared__ float xs[256];
    __shared__ float wsum[2];
    const _Float16* xp = x + (size_t)n * 256;
    xs[t] = (float)xp[t]; xs[t + 128] = (float)xp[t + 128];
    __syncthreads();
    float acc = bg0[t];
    for (int k = 0; k < 256; ++k) acc = fmaf(xs[k], Wg0[k * 128 + t], acc);
    acc = acc > 0.f ? acc : 0.f;
    float prod = acc * Wg1[t];
    prod = waveSum(prod);
    if ((t & 63) == 0) wsum[t >> 6] = prod;
    __syncthreads();
    if (t == 0) g[n] = wsum[0] + wsum[1] + bg1[0];
}

__global__ void k_group_bounds(const int* __restrict__ batch, int* __restrict__ gstart,
                               int* __restrict__ gend) {
    int n = blockIdx.x * 256 + threadIdx.x;
    if (n >= NN) return;
    int b = batch[n];
    if (n == 0 || batch[n - 1] != b) gstart[b] = n;
    if (n == NN - 1 || batch[n + 1] != b) gend[b] = n + 1;
}

// per-group softmax stats: m[g], invden[g]
__global__ __launch_bounds__(256) void k_pool_stats(
    const float* __restrict__ g, const int* __restrict__ gstart,
    const int* __restrict__ gend, float* __restrict__ mOut,
    float* __restrict__ invdenOut)
{
    int gi = blockIdx.x;
    int t = threadIdx.x;
    int s0 = gstart[gi], e0 = gend[gi];
    __shared__ float red[4];
    float mx = -1e30f;
    for (int n = s0 + t; n < e0; n += 256) mx = fmaxf(mx, g[n]);
    float wm = waveMax(mx);
    if ((t & 63) == 0) red[t >> 6] = wm;
    __syncthreads();
    float m = fmaxf(fmaxf(red[0], red[1]), fmaxf(red[2], red[3]));
    __syncthreads();
    float sm = 0.f;
    for (int n = s0 + t; n < e0; n += 256) sm += expf(g[n] - m);
    sm = waveSum(sm);
    if ((t & 63) == 0) red[t >> 6] = sm;
    __syncthreads();
    if (t == 0) {
        float den = red[0] + red[1] + red[2] + red[3] + 1e-16f;
        mOut[gi] = m;
        invdenOut[gi] = 1.f / den;
    }
}

#define PCH 16
__global__ __launch_bounds__(256) void k_pool_acc(
    const _Float16* __restrict__ x, const float* __restrict__ g,
    const int* __restrict__ batch, const float* __restrict__ m,
    const float* __restrict__ invden, float* __restrict__ hpool)
{
    int base = blockIdx.x * PCH;
    int t = threadIdx.x;
    float acc = 0.f;
    int cur = -1;
    for (int i = 0; i < PCH; ++i) {
        int n = base + i;
        if (n >= NN) break;
        int b = batch[n];
        if (b != cur) {
            if (cur >= 0) atomicAdd(&hpool[cur * 256 + t], acc);
            cur = b; acc = 0.f;
        }
        float w = expf(g[n] - m[b]) * invden[b];
        acc = fmaf(w, (float)x[(size_t)n * 256 + t], acc);
    }
    if (cur >= 0) atomicAdd(&hpool[cur * 256 + t], acc);
}

__global__ __launch_bounds__(256) void k_mlp(
    const float* __restrict__ hpool,
    const float* __restrict__ Wm0, const float* __restrict__ bm0,
    const float* __restrict__ Wm1, const float* __restrict__ bm1,
    const float* __restrict__ Wm2, const float* __restrict__ bm2,
    const float* __restrict__ Wm3, const float* __restrict__ bm3,
    const float* __restrict__ Wm4, const float* __restrict__ bm4,
    float* __restrict__ out)
{
    __shared__ float bufA[8 * 256];
    __shared__ float bufB[8 * 128];
    int t = threadIdx.x;
    for (int i = t; i < 8 * 256; i += 256) bufA[i] = hpool[i];
    __syncthreads();
    for (int i = t; i < 8 * 128; i += 256) {
        int r = i >> 7, c = i & 127;
        float acc = bm0[c];
        for (int k = 0; k < 256; ++k) acc = fmaf(bufA[r * 256 + k], Wm0[k * 128 + c], acc);
        bufB[i] = fmaxf(acc, 0.f);
    }
    __syncthreads();
    for (int i = t; i < 8 * 64; i += 256) {
        int r = i >> 6, c = i & 63;
        float acc = bm1[c];
        for (int k = 0; k < 128; ++k) acc = fmaf(bufB[r * 128 + k], Wm1[k * 64 + c], acc);
        bufA[i] = fmaxf(acc, 0.f);
    }
    __syncthreads();
    for (int i = t; i < 8 * 32; i += 256) {
        int r = i >> 5, c = i & 31;
        float acc = bm2[c];
        for (int k = 0; k < 64; ++k) acc = fmaf(bufA[r * 64 + k], Wm2[k * 32 + c], acc);
        bufB[i] = fmaxf(acc, 0.f);
    }
    __syncthreads();
    for (int i = t; i < 8 * 16; i += 256) {
        int r = i >> 4, c = i & 15;
        float acc = bm3[c];
        for (int k = 0; k < 32; ++k) acc = fmaf(bufB[r * 32 + k], Wm3[k * 16 + c], acc);
        bufA[i] = fmaxf(acc, 0.f);
    }
    __syncthreads();
    if (t < 8) {
        float acc = bm4[0];
        for (int k = 0; k < 16; ++k) acc = fmaf(bufA[t * 16 + k], Wm4[k], acc);
        out[t] = acc;
    }
}

// ---------------- host orchestration ----------------

static void run_gat_layer(const _Float16* ain, int K, int C,
                          const float* Wl, const float* bl,
                          const float* Wr, const float* br,
                          const float* att, const float* bias,
                          _Float16* wb0, _Float16* xlr,
                          const int* eoff, const int* slist,
                          _Float16* xout, hipStream_t stream)
{
    int HC = NH * C;
    dim3 tgrid(HC / 32, K / 32);
    k_cvtWT<<<tgrid, 256, 0, stream>>>(Wl, wb0, K, HC);
    k_cvtWT<<<tgrid, 256, 0, stream>>>(Wr, wb0 + (size_t)HC * K, K, HC);
    // fused Wl/Wr GEMM: N = 2*HC, output row n = [xl(n) | xr(n)]
    dim3 ggrid(2 * HC / 128, NNP / 128);
    gemm_mfma_f16<<<ggrid, 256, 0, stream>>>(ain, wb0, bl, br, HC, xlr, NN, K, 2 * HC);

    if (C == 1024)
        k_gat_fused<1024><<<NN, 256, 0, stream>>>(xlr, att, eoff, slist, bias, xout);
    else if (C == 512)
        k_gat_fused<512><<<NN, 256, 0, stream>>>(xlr, att, eoff, slist, bias, xout);
    else
        k_gat_fused<256><<<NN, 256, 0, stream>>>(xlr, att, eoff, slist, bias, xout);
}

extern "C" void kernel_launch(void* const* d_in, const int* in_sizes, int n_in,
                              void* d_out, int out_size, void* d_ws, size_t ws_size,
                              hipStream_t stream) {
    const float* x      = (const float*)d_in[0];
    const int* ei       = (const int*)d_in[1];
    const int* batch    = (const int*)d_in[2];
    const float* Wl1 = (const float*)d_in[3];  const float* bl1 = (const float*)d_in[4];
    const float* Wr1 = (const float*)d_in[5];  const float* br1 = (const float*)d_in[6];
    const float* att1= (const float*)d_in[7];  const float* b1  = (const float*)d_in[8];
    const float* Wl2 = (const float*)d_in[9];  const float* bl2 = (const float*)d_in[10];
    const float* Wr2 = (const float*)d_in[11]; const float* br2 = (const float*)d_in[12];
    const float* att2= (const float*)d_in[13]; const float* b2  = (const float*)d_in[14];
    const float* Wl3 = (const float*)d_in[15]; const float* bl3 = (const float*)d_in[16];
    const float* Wr3 = (const float*)d_in[17]; const float* br3 = (const float*)d_in[18];
    const float* att3= (const float*)d_in[19]; const float* b3  = (const float*)d_in[20];
    const float* Wm0 = (const float*)d_in[21]; const float* bm0 = (const float*)d_in[22];
    const float* Wm1 = (const float*)d_in[23]; const float* bm1 = (const float*)d_in[24];
    const float* Wm2 = (const float*)d_in[25]; const float* bm2 = (const float*)d_in[26];
    const float* Wm3 = (const float*)d_in[27]; const float* bm3 = (const float*)d_in[28];
    const float* Wm4 = (const float*)d_in[29]; const float* bm4 = (const float*)d_in[30];
    const float* Wg0 = (const float*)d_in[31]; const float* bg0 = (const float*)d_in[32];
    const float* Wg1 = (const float*)d_in[33]; const float* bg1 = (const float*)d_in[34];
    float* out = (float*)d_out;

    // workspace carve (float units = 4B); fp16 buffers 16B-aligned, padded rows
    float* ws = (float*)d_ws;
    size_t o = 0;
    _Float16* xlr = (_Float16*)(ws + o); o += (size_t)NNP * 8192 / 2;  // fused [xl|xr], layer1 sized
    _Float16* x1  = (_Float16*)(ws + o); o += (size_t)NNP * 1024 / 2;
    _Float16* x2  = (_Float16*)(ws + o); o += (size_t)NNP * 512 / 2;
    _Float16* x3  = (_Float16*)(ws + o); o += (size_t)NNP * 256 / 2;
    _Float16* a0p = (_Float16*)(ws + o); o += (size_t)NNP * 1536 / 2;
    _Float16* wb0 = (_Float16*)(ws + o); o += (size_t)8192 * 1536 / 2; // [WlT | WrT], layer1 sized
    int* srcA    = (int*)(ws + o); o += NEE;
    int* dstA    = (int*)(ws + o); o += NEE;
    int* cnt     = (int*)(ws + o); o += NN;
    int* eoff    = (int*)(ws + o); o += NN + 1;
    int* cur     = (int*)(ws + o); o += NN;
    int* slist   = (int*)(ws + o); o += NEE;
    float* g     = ws + o; o += NN;
    int* gstart  = (int*)(ws + o); o += NG;
    int* gend    = (int*)(ws + o); o += NG;
    float* gm    = ws + o; o += NG;
    float* ginv  = ws + o; o += NG;
    float* hpool = ws + o; o += NG * 256;

    // build CSR by dst (slist holds src node ids)
    int ebB = (NEE + 255) / 256;
    k_build_edges<<<ebB, 256, 0, stream>>>(ei, srcA, dstA);
    k_zero32<<<(NN + 255) / 256, 256, 0, stream>>>((unsigned int*)cnt, NN);
    k_count<<<ebB, 256, 0, stream>>>(dstA, cnt);
    k_scan<<<1, 256, 0, stream>>>(cnt, eoff, cur);
    k_fill<<<ebB, 256, 0, stream>>>(srcA, dstA, cur, slist);

    // layer-1 input -> fp16 (only conversion needed; later layers emit fp16)
    int nA = NN * 1536;
    k_cvtA<<<(nA + 255) / 256, 256, 0, stream>>>(x, a0p, nA);

    // three GATv2 layers
    run_gat_layer(a0p, 1536, 1024, Wl1, bl1, Wr1, br1, att1, b1,
                  wb0, xlr, eoff, slist, x1, stream);
    run_gat_layer(x1,  1024, 512,  Wl2, bl2, Wr2, br2, att2, b2,
                  wb0, xlr, eoff, slist, x2, stream);
    run_gat_layer(x2,  512,  256,  Wl3, bl3, Wr3, br3, att3, b3,
                  wb0, xlr, eoff, slist, x3, stream);

    // gate + pool + MLP
    k_gate<<<NN, 128, 0, stream>>>(x3, Wg0, bg0, Wg1, bg1, g);
    k_zero32<<<1, 64, 0, stream>>>((unsigned int*)gstart, 2 * NG);
    k_group_bounds<<<(NN + 255) / 256, 256, 0, stream>>>(batch, gstart, gend);
    k_pool_stats<<<NG, 256, 0, stream>>>(g, gstart, gend, gm, ginv);
    k_zero32<<<(NG * 256 + 255) / 256, 256, 0, stream>>>((unsigned int*)hpool, NG * 256);
    k_pool_acc<<<(NN + PCH - 1) / PCH, 256, 0, stream>>>(x3, g, batch, gm, ginv, hpool);
    k_mlp<<<1, 256, 0, stream>>>(hpool, Wm0, bm0, Wm1, bm1, Wm2, bm2,
                                 Wm3, bm3, Wm4, bm4, out);
}

// Round 3
// 695.639 us; speedup vs baseline: 1.1102x; 1.0058x over previous
//
#include <hip/hip_runtime.h>
#include <math.h>

// Problem constants (from reference)
#define NN 5000
#define NNP 5120    // padded rows for GEMM A-operand OOB staging
#define NE 50000
#define NEE 55000   // edges + self loops
#define NG 8
#define NH 4

typedef __attribute__((ext_vector_type(8))) _Float16 half8;
typedef __attribute__((ext_vector_type(4))) _Float16 half4;
typedef __attribute__((ext_vector_type(4))) float floatx4;

// ---------------- utility device functions ----------------

__device__ inline float waveSum(float v) {
    #pragma unroll
    for (int o = 32; o > 0; o >>= 1) v += __shfl_xor(v, o, 64);
    return v;
}
__device__ inline float waveMax(float v) {
    #pragma unroll
    for (int o = 32; o > 0; o >>= 1) v = fmaxf(v, __shfl_xor(v, o, 64));
    return v;
}

// async global->LDS DMA, 16B per lane; lds dest is wave-uniform base + lane*16
__device__ __forceinline__ void gload_lds16(const _Float16* g, _Float16* l) {
    __builtin_amdgcn_global_load_lds(
        (__attribute__((address_space(1))) void*)g,
        (__attribute__((address_space(3))) void*)l,
        16, 0, 0);
}

template<int N>
__device__ __forceinline__ void vmgate() {
    if constexpr (N == 0) asm volatile("s_waitcnt vmcnt(0)" ::: "memory");
    else if constexpr (N == 2) asm volatile("s_waitcnt vmcnt(2)" ::: "memory");
    else if constexpr (N == 4) asm volatile("s_waitcnt vmcnt(4)" ::: "memory");
    // N < 0: no gate
}

// ---------------- fp32 -> fp16 conversion ----------------

__global__ void k_cvtA(const float* __restrict__ X, _Float16* __restrict__ A0, int n) {
    int i = blockIdx.x * 256 + threadIdx.x;
    if (i >= n) return;
    A0[i] = (_Float16)X[i];
}

// W (K x M fp32) -> B0 fp16 TRANSPOSED to (M x K)
__global__ __launch_bounds__(256) void k_cvtWT(const float* __restrict__ W,
        _Float16* __restrict__ B0, int K, int M)
{
    __shared__ float tile[32][33];
    int m0 = blockIdx.x * 32, k0 = blockIdx.y * 32;
    int tx = threadIdx.x & 31, ty = threadIdx.x >> 5;
    #pragma unroll
    for (int i = 0; i < 4; ++i)
        tile[ty + 8 * i][tx] = W[(size_t)(k0 + ty + 8 * i) * M + m0 + tx];
    __syncthreads();
    #pragma unroll
    for (int i = 0; i < 4; ++i) {
        int mm = ty + 8 * i, kk = tx;
        B0[(size_t)(m0 + mm) * K + kk + k0] = (_Float16)tile[kk][mm];
    }
}

// ============ 256x256 / BK=64 / 8-wave phase-split GEMM (T2+T3+T4+T5) ======
// C(Mrows x N) = A @ B^T + bias (biasL for cols<Nhalf, biasR above).
// The R2 128x128 2-barrier kernel measured 717 TF (MfmaUtil 33%) = the known
// m97-structure ceiling: 16 MFMA/wave per K-step can't cover staging latency
// and every __syncthreads drains vmcnt(0). This kernel is the catalog's
// 8-phase template: per K-tile (BK=64) 4 phases, each = {12 ds_read_b128
// (one C-quadrant's frags) | 2 global_load_lds stage calls (next tile) |
// barrier | setprio(1) 16 MFMA setprio(0) | counted-vmcnt gate | barrier}.
// Stage-unit order per tile: Ah0,Ah1,Bh0,Bh1 (2 calls each). Gates:
//  - end of tile (after ph4): vmcnt(2)  -> units Ah0',Ah1',Bh0' landed,
//    Bh1' (2 newest) stays in flight across the barrier.
//  - after ph2: vmcnt(4) -> this tile's Bh1 landed (needed ph3/4); the 4
//    newest (next tile Ah0',Ah1') stay outstanding.
// LDS swizzle (both-sides-or-neither, m173/m231): rows are 64 halfs = 8
// chunks of 16B; staging pre-swizzles the per-lane GLOBAL chunk
// (c ^ (row&7)) with a linear LDS dest; fragment reads XOR the same key ->
// each 16-lane group covers all 8 chunk positions = conflict-free b128.
__global__ __launch_bounds__(512, 2) void gemm256_mfma_f16(
    const _Float16* __restrict__ A0, const _Float16* __restrict__ B0,
    const float* __restrict__ biasL, const float* __restrict__ biasR,
    int Nhalf, _Float16* __restrict__ C,
    int Mrows, int K, int N)
{
    // [dbuf][ A 256*64 | B 256*64 ] halfs = 128 KB total
    __shared__ __align__(16) _Float16 smem[2 * 32768];

    const int tid  = threadIdx.x;
    const int wave = tid >> 6;
    const int lane = tid & 63;
    const int wr = wave >> 2;      // 0..1  (M half of a quadrant)
    const int wc = wave & 3;       // 0..3  (N quarter of a quadrant)
    const int rowBase = blockIdx.y * 256;
    const int colBase = blockIdx.x * 256;

    floatx4 acc[2][2][4][2];
    #pragma unroll
    for (int qa = 0; qa < 2; ++qa)
        #pragma unroll
        for (int qb = 0; qb < 2; ++qb)
            #pragma unroll
            for (int f = 0; f < 4; ++f)
                #pragma unroll
                for (int g = 0; g < 2; ++g)
                    acc[qa][qb][f][g] = (floatx4){0.f, 0.f, 0.f, 0.f};

    // staging: wave w stages rows h*128 + w*16 .. +16 of A and of B per tile
    // (2 calls of 8 rows each). lane -> row lane>>3, lds chunk lane&7,
    // global chunk (lane&7)^(lane>>3)  [row&7 == lane>>3 at 8-row alignment]
    const int srow   = lane >> 3;
    const int schunk = ((lane & 7) ^ srow) << 3;   // halfs
    const _Float16* gA = A0 + (size_t)(rowBase + wave * 16 + srow) * K + schunk;
    const _Float16* gB = B0 + (size_t)(colBase + wave * 16 + srow) * K + schunk;
    const size_t rstep = (size_t)8 * K;
    const size_t hstep = (size_t)128 * K;

    auto stageA = [&](int b, int h, int kt) {
        _Float16* l = &smem[b * 32768 + (h * 128 + wave * 16) * 64];
        const _Float16* g = gA + (size_t)h * hstep + (size_t)kt * 64;
        gload_lds16(g, l);
        gload_lds16(g + rstep, l + 512);
    };
    auto stageB = [&](int b, int h, int kt) {
        _Float16* l = &smem[b * 32768 + 16384 + (h * 128 + wave * 16) * 64];
        const _Float16* g = gB + (size_t)h * hstep + (size_t)kt * 64;
        gload_lds16(g, l);
        gload_lds16(g + rstep, l + 512);
    };

    // one phase: C-quadrant (QA,QB), frag reads + stage + MFMA + gate
    auto phase = [&](auto qa_c, auto qb_c, auto gate_c, const _Float16* Ab,
                     const _Float16* Bb, auto stg) {
        constexpr int QA = decltype(qa_c)::value;
        constexpr int QB = decltype(qb_c)::value;
        constexpr int GATE = decltype(gate_c)::value;
        const int lm = lane & 15;
        const int key = lane & 7;
        const int kg = lane >> 4;
        half8 af[4][2], bf[2][2];
        #pragma unroll
        for (int f = 0; f < 4; ++f)
            #pragma unroll
            for (int s = 0; s < 2; ++s) {
                int row = QA * 128 + wr * 64 + f * 16 + lm;
                int ch = (s * 4 + kg) ^ key;
                af[f][s] = *(const half8*)&Ab[row * 64 + ch * 8];
            }
        #pragma unroll
        for (int g = 0; g < 2; ++g)
            #pragma unroll
            for (int s = 0; s < 2; ++s) {
                int row = QB * 128 + wc * 32 + g * 16 + lm;
                int ch = (s * 4 + kg) ^ key;
                bf[g][s] = *(const half8*)&Bb[row * 64 + ch * 8];
            }
        stg();
        __builtin_amdgcn_s_barrier();
        __builtin_amdgcn_s_setprio(1);
        #pragma unroll
        for (int f = 0; f < 4; ++f)
            #pragma unroll
            for (int g = 0; g < 2; ++g)
                #pragma unroll
                for (int s = 0; s < 2; ++s)
                    acc[QA][QB][f][g] = __builtin_amdgcn_mfma_f32_16x16x32_f16(
                        af[f][s], bf[g][s], acc[QA][QB][f][g], 0, 0, 0);
        __builtin_amdgcn_s_setprio(0);
        vmgate<GATE>();
        __builtin_amdgcn_s_barrier();
        __builtin_amdgcn_sched_barrier(0);
    };

    auto ic = [](auto v) { return v; };
    using i0 = std::integral_constant<int, 0>;
    using i1 = std::integral_constant<int, 1>;
    using gN = std::integral_constant<int, -1>;
    using g0 = std::integral_constant<int, 0>;
    using g2 = std::integral_constant<int, 2>;
    using g4 = std::integral_constant<int, 4>;
    (void)ic;

    // prologue: tile 0 -> buf 0 (all 4 units), gate 2, barrier
    stageA(0, 0, 0); stageA(0, 1, 0); stageB(0, 0, 0); stageB(0, 1, 0);
    vmgate<2>();
    __builtin_amdgcn_s_barrier();

    const int nk = K >> 6;
    for (int t = 0; t < nk - 1; ++t) {
        const int b = t & 1;
        const _Float16* Ab = &smem[b * 32768];
        const _Float16* Bb = Ab + 16384;
        phase(i0{}, i0{}, gN{}, Ab, Bb, [&]{ stageA(b ^ 1, 0, t + 1); });
        phase(i1{}, i0{}, g4{}, Ab, Bb, [&]{ stageA(b ^ 1, 1, t + 1); });
        phase(i0{}, i1{}, gN{}, Ab, Bb, [&]{ stageB(b ^ 1, 0, t + 1); });
        phase(i1{}, i1{}, g2{}, Ab, Bb, [&]{ stageB(b ^ 1, 1, t + 1); });
    }
    {   // last tile: no staging; drain Bh1 before ph3
        const int b = (nk - 1) & 1;
        const _Float16* Ab = &smem[b * 32768];
        const _Float16* Bb = Ab + 16384;
        phase(i0{}, i0{}, gN{}, Ab, Bb, [&]{});
        phase(i1{}, i0{}, g0{}, Ab, Bb, [&]{});
        phase(i0{}, i1{}, gN{}, Ab, Bb, [&]{});
        phase(i1{}, i1{}, gN{}, Ab, Bb, [&]{});
    }

    // ---- coalesced epilogue: stage 256x256 C-tile in the dead LDS ----
    // 32B-granule XOR by (row>>2)&7: the 4 lane-groups (rows +0/4/8/12) of a
    // frag store land in 4 distinct bank quadrants; bijective per row.
    _Float16* Ct = smem;
    const int lm = lane & 15;
    const int cq = (lane >> 4) * 4;
    #pragma unroll
    for (int qb = 0; qb < 2; ++qb)
        #pragma unroll
        for (int g = 0; g < 2; ++g) {
            int col = qb * 128 + wc * 32 + g * 16 + lm;
            int gcol = colBase + col;
            float bv = (gcol < Nhalf) ? biasL[gcol] : biasR[gcol - Nhalf];
            #pragma unroll
            for (int qa = 0; qa < 2; ++qa)
                #pragma unroll
                for (int f = 0; f < 4; ++f)
                    #pragma unroll
                    for (int r = 0; r < 4; ++r) {
                        int row = qa * 128 + wr * 64 + f * 16 + cq + r;
                        int gi = (col >> 4) ^ ((row >> 2) & 7);
                        Ct[row * 256 + gi * 16 + (col & 15)] =
                            (_Float16)(acc[qa][qb][f][g][r] + bv);
                    }
        }
    __syncthreads();
    // 512 threads store 16 rows/pass (row = 512B contiguous), 16 passes
    const int r0 = tid >> 5;           // 0..15
    const int cc = (tid & 31) * 8;     // halfs within row
    const int gg = cc >> 4;
    #pragma unroll
    for (int ps = 0; ps < 16; ++ps) {
        int row = ps * 16 + r0;
        int grow = rowBase + row;
        if (grow < Mrows) {
            int gp = gg ^ ((row >> 2) & 7);
            half8 v = *(const half8*)&Ct[row * 256 + gp * 16 + (cc & 15)];
            *(half8*)&C[(size_t)grow * N + colBase + cc] = v;
        }
    }
}

// ---------------- 128x128 MFMA GEMM (proven R2 kernel; layer-3) ------------
__global__ __launch_bounds__(256) void gemm_mfma_f16(
    const _Float16* __restrict__ A0, const _Float16* __restrict__ B0,
    const float* __restrict__ biasL, const float* __restrict__ biasR,
    int Nhalf, _Float16* __restrict__ C,
    int Mrows, int K, int N)
{
    __shared__ __align__(16) _Float16 smem[2 * 2 * 128 * 32];
    _Float16* As = smem;
    _Float16* Bs = smem + 2 * 128 * 32;

    const int tid = threadIdx.x;
    const int wave = tid >> 6;
    const int lane = tid & 63;
    const int wm = (wave >> 1) * 64;
    const int wn = (wave & 1) * 64;
    const int lm = lane & 15;
    const int swz = (((lane >> 4) ^ ((lane >> 1) & 3)) << 3);

    const int rowBase = blockIdx.y * 128;
    const int colBase = blockIdx.x * 128;

    floatx4 acc[4][4];
    #pragma unroll
    for (int i = 0; i < 4; ++i)
        #pragma unroll
        for (int j = 0; j < 4; ++j)
            acc[i][j] = (floatx4){0.f, 0.f, 0.f, 0.f};

    const int sr = lane >> 2;
    const int scol = (((lane & 3) ^ ((lane >> 3) & 3)) << 3);
    const _Float16* gA = A0 + (size_t)(rowBase + wave * 32 + sr) * K + scol;
    const _Float16* gB = B0 + (size_t)(colBase + wave * 32 + sr) * K + scol;
    const size_t skip16 = (size_t)16 * K;
    const int lo0 = (wave * 32) * 32;
    const int lo1 = (wave * 32 + 16) * 32;

    gload_lds16(gA, &As[lo0]);
    gload_lds16(gA + skip16, &As[lo1]);
    gload_lds16(gB, &Bs[lo0]);
    gload_lds16(gB + skip16, &Bs[lo1]);
    __syncthreads();

    const int nk = K >> 5;
    for (int t = 0; t < nk; ++t) {
        const int p = t & 1;
        const int po = p * 128 * 32;
        if (t + 1 < nk) {
            const int k1 = (t + 1) << 5;
            const int qo = (p ^ 1) * 128 * 32;
            gload_lds16(gA + k1, &As[qo + lo0]);
            gload_lds16(gA + skip16 + k1, &As[qo + lo1]);
            gload_lds16(gB + k1, &Bs[qo + lo0]);
            gload_lds16(gB + skip16 + k1, &Bs[qo + lo1]);
        }
        half8 a0[4], b0[4];
        #pragma unroll
        for (int i = 0; i < 4; ++i) {
            a0[i] = *(const half8*)&As[po + (wm + i * 16 + lm) * 32 + swz];
            b0[i] = *(const half8*)&Bs[po + (wn + i * 16 + lm) * 32 + swz];
        }
        #pragma unroll
        for (int i = 0; i < 4; ++i)
            #pragma unroll
            for (int j = 0; j < 4; ++j)
                acc[i][j] = __builtin_amdgcn_mfma_f32_16x16x32_f16(a0[i], b0[j], acc[i][j], 0, 0, 0);
        __syncthreads();
    }

    _Float16* Ct = smem;
    const int cq = (lane >> 4) * 4;
    #pragma unroll
    for (int j = 0; j < 4; ++j) {
        int col = wn + j * 16 + lm;
        int gcol = colBase + col;
        float bv = (gcol < Nhalf) ? biasL[gcol] : biasR[gcol - Nhalf];
        #pragma unroll
        for (int i = 0; i < 4; ++i) {
            int row = wm + i * 16 + cq;
            #pragma unroll
            for (int r = 0; r < 4; ++r) {
                int rr = row + r;
                Ct[rr * 128 + (col ^ (((rr >> 2) & 7) << 4))] = (_Float16)(acc[i][j][r] + bv);
            }
        }
    }
    __syncthreads();
    const int r0 = tid >> 4;
    const int cc = (tid & 15) * 8;
    #pragma unroll
    for (int ps = 0; ps < 8; ++ps) {
        int row = ps * 16 + r0;
        int grow = rowBase + row;
        if (grow < Mrows) {
            half8 v = *(const half8*)&Ct[row * 128 + (cc ^ (((row >> 2) & 7) << 4))];
            *(half8*)&C[(size_t)grow * N + colBase + cc] = v;
        }
    }
}

// ---------------- CSR build ----------------

__global__ void k_build_edges(const int* __restrict__ ei, int* __restrict__ src,
                              int* __restrict__ dst) {
    int i = blockIdx.x * 256 + threadIdx.x;
    if (i < NE) { src[i] = ei[i]; dst[i] = ei[NE + i]; }
    else if (i < NEE) { src[i] = i - NE; dst[i] = i - NE; }
}

__global__ void k_zero32(unsigned int* __restrict__ p, int n) {
    int i = blockIdx.x * 256 + threadIdx.x;
    if (i < n) p[i] = 0u;
}

__global__ void k_count(const int* __restrict__ dst, int* __restrict__ cnt) {
    int i = blockIdx.x * 256 + threadIdx.x;
    if (i < NEE) atomicAdd(&cnt[dst[i]], 1);
}

__global__ __launch_bounds__(256) void k_scan(const int* __restrict__ cnt,
                                              int* __restrict__ off, int* __restrict__ cur) {
    __shared__ int partial[256];
    __shared__ int ppre[257];
    int t = threadIdx.x;
    const int chunk = (NN + 255) / 256;
    int lo = t * chunk, hi = min(NN, (t + 1) * chunk);
    int s = 0;
    for (int i = lo; i < hi; ++i) s += cnt[i];
    partial[t] = s;
    __syncthreads();
    if (t == 0) {
        int acc = 0;
        for (int i = 0; i < 256; ++i) { ppre[i] = acc; acc += partial[i]; }
        ppre[256] = acc;
    }
    __syncthreads();
    int acc = ppre[t];
    for (int i = lo; i < hi; ++i) { off[i] = acc; cur[i] = acc; acc += cnt[i]; }
    if (t == 0) off[NN] = ppre[256];
}

__global__ void k_fill(const int* __restrict__ src, const int* __restrict__ dst,
                       int* __restrict__ cur, int* __restrict__ slist) {
    int e = blockIdx.x * 256 + threadIdx.x;
    if (e < NEE) { int p = atomicAdd(&cur[dst[e]], 1); slist[p] = src[e]; }
}

// ---------------- fused GATv2 edge pipeline (fp16 activations) -------------
template<int C>
__global__ __launch_bounds__(256) void k_gat_fused(
    const _Float16* __restrict__ xlr, const float* __restrict__ att,
    const int* __restrict__ eoff, const int* __restrict__ slist,
    const float* __restrict__ bias, _Float16* __restrict__ out)
{
    constexpr int LD = 2 * NH * C;          // fused GEMM row stride (halfs)
    constexpr int CH = (C >= 512) ? 8 : 4;  // halfs per load per lane
    constexpr int NC = C / (64 * CH);       // chunks per head-row
    constexpr int PL = NC * CH;             // elems per lane
    __shared__ float red[NH * C];
    const int n = blockIdx.x;
    const int h = threadIdx.x >> 6;
    const int lane = threadIdx.x & 63;

    float xrv[PL], attv[PL], acc[PL];
    {
        const _Float16* xrrow = xlr + (size_t)n * LD + NH * C + h * C + lane * CH;
        const float* ah = att + h * C + lane * CH;
        #pragma unroll
        for (int c = 0; c < NC; ++c) {
            if constexpr (CH == 8) {
                half8 hv = *(const half8*)(xrrow + c * 64 * CH);
                #pragma unroll
                for (int e = 0; e < 8; ++e) xrv[c * 8 + e] = (float)hv[e];
            } else {
                half4 hv = *(const half4*)(xrrow + c * 64 * CH);
                #pragma unroll
                for (int e = 0; e < 4; ++e) xrv[c * 4 + e] = (float)hv[e];
            }
            #pragma unroll
            for (int e = 0; e < CH; e += 4) {
                float4 a4 = *(const float4*)(ah + c * 64 * CH + e);
                attv[c * CH + e + 0] = a4.x; attv[c * CH + e + 1] = a4.y;
                attv[c * CH + e + 2] = a4.z; attv[c * CH + e + 3] = a4.w;
            }
        }
        #pragma unroll
        for (int e = 0; e < PL; ++e) acc[e] = 0.f;
    }

    float m = -INFINITY, den = 0.f;
    const int start = eoff[n], end = eoff[n + 1];

    _Float16 bufA[PL], bufB[PL];
    auto ldrow = [&](int s, _Float16* buf) {
        const _Float16* p = xlr + (size_t)s * LD + h * C + lane * CH;
        #pragma unroll
        for (int c = 0; c < NC; ++c) {
            if constexpr (CH == 8)
                *(half8*)&buf[c * 8] = *(const half8*)(p + c * 64 * CH);
            else
                *(half4*)&buf[c * 4] = *(const half4*)(p + c * 64 * CH);
        }
    };

    if (start < end) ldrow(slist[start], bufA);
    for (int j = start; j < end; ++j) {
        if (j + 1 < end) ldrow(slist[j + 1], bufB);   // prefetch next src row
        float xv[PL];
        float ps = 0.f;
        #pragma unroll
        for (int e = 0; e < PL; ++e) {
            xv[e] = (float)bufA[e];
            float v = xv[e] + xrv[e];
            v = v > 0.f ? v : 0.2f * v;
            ps = fmaf(v, attv[e], ps);
        }
        ps = waveSum(ps);
        float m_new = fmaxf(m, ps);
        float scale = expf(m - m_new);
        float ex = expf(ps - m_new);
        den = den * scale + ex;
        m = m_new;
        #pragma unroll
        for (int e = 0; e < PL; ++e)
            acc[e] = fmaf(ex, xv[e], acc[e] * scale);
        #pragma unroll
        for (int e = 0; e < PL; ++e) bufA[e] = bufB[e];
    }

    float inv = 1.f / (den + 1e-16f);
    #pragma unroll
    for (int c = 0; c < NC; ++c) {
        int off = h * C + c * 64 * CH + lane * CH;
        #pragma unroll
        for (int e = 0; e < CH; e += 4) {
            float4 r;
            r.x = acc[c * CH + e + 0] * inv;
            r.y = acc[c * CH + e + 1] * inv;
            r.z = acc[c * CH + e + 2] * inv;
            r.w = acc[c * CH + e + 3] * inv;
            *(float4*)&red[off + e] = r;
        }
    }
    __syncthreads();

    int t = threadIdx.x;
    for (int c4 = t; c4 < C / 4; c4 += 256) {
        int c = c4 * 4;
        float4 r0 = *(const float4*)&red[0 * C + c];
        float4 r1 = *(const float4*)&red[1 * C + c];
        float4 r2 = *(const float4*)&red[2 * C + c];
        float4 r3 = *(const float4*)&red[3 * C + c];
        float4 bv = *(const float4*)(bias + c);
        half4 o;
        o[0] = (_Float16)fmaxf((r0.x + r1.x + r2.x + r3.x) * 0.25f + bv.x, 0.f);
        o[1] = (_Float16)fmaxf((r0.y + r1.y + r2.y + r3.y) * 0.25f + bv.y, 0.f);
        o[2] = (_Float16)fmaxf((r0.z + r1.z + r2.z + r3.z) * 0.25f + bv.z, 0.f);
        o[3] = (_Float16)fmaxf((r0.w + r1.w + r2.w + r3.w) * 0.25f + bv.w, 0.f);
        *(half4*)(out + (size_t)n * C + c) = o;
    }
}

// ---------------- gate + pool + MLP ----------------

__global__ __launch_bounds__(128) void k_gate(
    const _Float16* __restrict__ x, const float* __restrict__ Wg0,
    const float* __restrict__ bg0, const float* __restrict__ Wg1,
    const float* __restrict__ bg1, float* __restrict__ g)
{
    int n = blockIdx.x;
    int t = threadIdx.x;
    __shared__ float xs[256];
    __shared__ float wsum[2];
    const _Float16* xp = x + (size_t)n * 256;
    xs[t] = (float)xp[t]; xs[t + 128] = (float)xp[t + 128];
    __syncthreads();
    float acc = bg0[t];
    for (int k = 0; k < 256; ++k) acc = fmaf(xs[k], Wg0[k * 128 + t], acc);
    acc = acc > 0.f ? acc : 0.f;
    float prod = acc * Wg1[t];
    prod = waveSum(prod);
    if ((t & 63) == 0) wsum[t >> 6] = prod;
    __syncthreads();
    if (t == 0) g[n] = wsum[0] + wsum[1] + bg1[0];
}

__global__ void k_group_bounds(const int* __restrict__ batch, int* __restrict__ gstart,
                               int* __restrict__ gend) {
    int n = blockIdx.x * 256 + threadIdx.x;
    if (n >= NN) return;
    int b = batch[n];
    if (n == 0 || batch[n - 1] != b) gstart[b] = n;
    if (n == NN - 1 || batch[n + 1] != b) gend[b] = n + 1;
}

// per-group softmax stats: m[g], invden[g]
__global__ __launch_bounds__(256) void k_pool_stats(
    const float* __restrict__ g, const int* __restrict__ gstart,
    const int* __restrict__ gend, float* __restrict__ mOut,
    float* __restrict__ invdenOut)
{
    int gi = blockIdx.x;
    int t = threadIdx.x;
    int s0 = gstart[gi], e0 = gend[gi];
    __shared__ float red[4];
    float mx = -1e30f;
    for (int n = s0 + t; n < e0; n += 256) mx = fmaxf(mx, g[n]);
    float wm = waveMax(mx);
    if ((t & 63) == 0) red[t >> 6] = wm;
    __syncthreads();
    float m = fmaxf(fmaxf(red[0], red[1]), fmaxf(red[2], red[3]));
    __syncthreads();
    float sm = 0.f;
    for (int n = s0 + t; n < e0; n += 256) sm += expf(g[n] - m);
    sm = waveSum(sm);
    if ((t & 63) == 0) red[t >> 6] = sm;
    __syncthreads();
    if (t == 0) {
        float den = red[0] + red[1] + red[2] + red[3] + 1e-16f;
        mOut[gi] = m;
        invdenOut[gi] = 1.f / den;
    }
}

#define PCH 16
__global__ __launch_bounds__(256) void k_pool_acc(
    const _Float16* __restrict__ x, const float* __restrict__ g,
    const int* __restrict__ batch, const float* __restrict__ m,
    const float* __restrict__ invden, float* __restrict__ hpool)
{
    int base = blockIdx.x * PCH;
    int t = threadIdx.x;
    float acc = 0.f;
    int cur = -1;
    for (int i = 0; i < PCH; ++i) {
        int n = base + i;
        if (n >= NN) break;
        int b = batch[n];
        if (b != cur) {
            if (cur >= 0) atomicAdd(&hpool[cur * 256 + t], acc);
            cur = b; acc = 0.f;
        }
        float w = expf(g[n] - m[b]) * invden[b];
        acc = fmaf(w, (float)x[(size_t)n * 256 + t], acc);
    }
    if (cur >= 0) atomicAdd(&hpool[cur * 256 + t], acc);
}

__global__ __launch_bounds__(256) void k_mlp(
    const float* __restrict__ hpool,
    const float* __restrict__ Wm0, const float* __restrict__ bm0,
    const float* __restrict__ Wm1, const float* __restrict__ bm1,
    const float* __restrict__ Wm2, const float* __restrict__ bm2,
    const float* __restrict__ Wm3, const float* __restrict__ bm3,
    const float* __restrict__ Wm4, const float* __restrict__ bm4,
    float* __restrict__ out)
{
    __shared__ float bufA[8 * 256];
    __shared__ float bufB[8 * 128];
    int t = threadIdx.x;
    for (int i = t; i < 8 * 256; i += 256) bufA[i] = hpool[i];
    __syncthreads();
    for (int i = t; i < 8 * 128; i += 256) {
        int r = i >> 7, c = i & 127;
        float acc = bm0[c];
        for (int k = 0; k < 256; ++k) acc = fmaf(bufA[r * 256 + k], Wm0[k * 128 + c], acc);
        bufB[i] = fmaxf(acc, 0.f);
    }
    __syncthreads();
    for (int i = t; i < 8 * 64; i += 256) {
        int r = i >> 6, c = i & 63;
        float acc = bm1[c];
        for (int k = 0; k < 128; ++k) acc = fmaf(bufB[r * 128 + k], Wm1[k * 64 + c], acc);
        bufA[i] = fmaxf(acc, 0.f);
    }
    __syncthreads();
    for (int i = t; i < 8 * 32; i += 256) {
        int r = i >> 5, c = i & 31;
        float acc = bm2[c];
        for (int k = 0; k < 64; ++k) acc = fmaf(bufA[r * 64 + k], Wm2[k * 32 + c], acc);
        bufB[i] = fmaxf(acc, 0.f);
    }
    __syncthreads();
    for (int i = t; i < 8 * 16; i += 256) {
        int r = i >> 4, c = i & 15;
        float acc = bm3[c];
        for (int k = 0; k < 32; ++k) acc = fmaf(bufB[r * 32 + k], Wm3[k * 16 + c], acc);
        bufA[i] = fmaxf(acc, 0.f);
    }
    __syncthreads();
    if (t < 8) {
        float acc = bm4[0];
        for (int k = 0; k < 16; ++k) acc = fmaf(bufA[t * 16 + k], Wm4[k], acc);
        out[t] = acc;
    }
}

// ---------------- host orchestration ----------------

static void run_gat_layer(const _Float16* ain, int K, int C,
                          const float* Wl, const float* bl,
                          const float* Wr, const float* br,
                          const float* att, const float* bias,
                          _Float16* wb0, _Float16* xlr,
                          const int* eoff, const int* slist,
                          _Float16* xout, hipStream_t stream)
{
    int HC = NH * C;
    dim3 tgrid(HC / 32, K / 32);
    k_cvtWT<<<tgrid, 256, 0, stream>>>(Wl, wb0, K, HC);
    k_cvtWT<<<tgrid, 256, 0, stream>>>(Wr, wb0 + (size_t)HC * K, K, HC);
    // fused Wl/Wr GEMM: N = 2*HC, output row n = [xl(n) | xr(n)]
    if (C >= 512) {
        dim3 ggrid(2 * HC / 256, NNP / 256);
        gemm256_mfma_f16<<<ggrid, 512, 0, stream>>>(ain, wb0, bl, br, HC, xlr, NN, K, 2 * HC);
    } else {
        dim3 ggrid(2 * HC / 128, NNP / 128);
        gemm_mfma_f16<<<ggrid, 256, 0, stream>>>(ain, wb0, bl, br, HC, xlr, NN, K, 2 * HC);
    }

    if (C == 1024)
        k_gat_fused<1024><<<NN, 256, 0, stream>>>(xlr, att, eoff, slist, bias, xout);
    else if (C == 512)
        k_gat_fused<512><<<NN, 256, 0, stream>>>(xlr, att, eoff, slist, bias, xout);
    else
        k_gat_fused<256><<<NN, 256, 0, stream>>>(xlr, att, eoff, slist, bias, xout);
}

extern "C" void kernel_launch(void* const* d_in, const int* in_sizes, int n_in,
                              void* d_out, int out_size, void* d_ws, size_t ws_size,
                              hipStream_t stream) {
    const float* x      = (const float*)d_in[0];
    const int* ei       = (const int*)d_in[1];
    const int* batch    = (const int*)d_in[2];
    const float* Wl1 = (const float*)d_in[3];  const float* bl1 = (const float*)d_in[4];
    const float* Wr1 = (const float*)d_in[5];  const float* br1 = (const float*)d_in[6];
    const float* att1= (const float*)d_in[7];  const float* b1  = (const float*)d_in[8];
    const float* Wl2 = (const float*)d_in[9];  const float* bl2 = (const float*)d_in[10];
    const float* Wr2 = (const float*)d_in[11]; const float* br2 = (const float*)d_in[12];
    const float* att2= (const float*)d_in[13]; const float* b2  = (const float*)d_in[14];
    const float* Wl3 = (const float*)d_in[15]; const float* bl3 = (const float*)d_in[16];
    const float* Wr3 = (const float*)d_in[17]; const float* br3 = (const float*)d_in[18];
    const float* att3= (const float*)d_in[19]; const float* b3  = (const float*)d_in[20];
    const float* Wm0 = (const float*)d_in[21]; const float* bm0 = (const float*)d_in[22];
    const float* Wm1 = (const float*)d_in[23]; const float* bm1 = (const float*)d_in[24];
    const float* Wm2 = (const float*)d_in[25]; const float* bm2 = (const float*)d_in[26];
    const float* Wm3 = (const float*)d_in[27]; const float* bm3 = (const float*)d_in[28];
    const float* Wm4 = (const float*)d_in[29]; const float* bm4 = (const float*)d_in[30];
    const float* Wg0 = (const float*)d_in[31]; const float* bg0 = (const float*)d_in[32];
    const float* Wg1 = (const float*)d_in[33]; const float* bg1 = (const float*)d_in[34];
    float* out = (float*)d_out;

    // workspace carve (float units = 4B); fp16 buffers 16B-aligned, padded rows
    float* ws = (float*)d_ws;
    size_t o = 0;
    _Float16* xlr = (_Float16*)(ws + o); o += (size_t)NNP * 8192 / 2;  // fused [xl|xr], layer1 sized
    _Float16* x1  = (_Float16*)(ws + o); o += (size_t)NNP * 1024 / 2;
    _Float16* x2  = (_Float16*)(ws + o); o += (size_t)NNP * 512 / 2;
    _Float16* x3  = (_Float16*)(ws + o); o += (size_t)NNP * 256 / 2;
    _Float16* a0p = (_Float16*)(ws + o); o += (size_t)NNP * 1536 / 2;
    _Float16* wb0 = (_Float16*)(ws + o); o += (size_t)8192 * 1536 / 2; // [WlT | WrT], layer1 sized
    int* srcA    = (int*)(ws + o); o += NEE;
    int* dstA    = (int*)(ws + o); o += NEE;
    int* cnt     = (int*)(ws + o); o += NN;
    int* eoff    = (int*)(ws + o); o += NN + 1;
    int* cur     = (int*)(ws + o); o += NN;
    int* slist   = (int*)(ws + o); o += NEE;
    float* g     = ws + o; o += NN;
    int* gstart  = (int*)(ws + o); o += NG;
    int* gend    = (int*)(ws + o); o += NG;
    float* gm    = ws + o; o += NG;
    float* ginv  = ws + o; o += NG;
    float* hpool = ws + o; o += NG * 256;

    // build CSR by dst (slist holds src node ids)
    int ebB = (NEE + 255) / 256;
    k_build_edges<<<ebB, 256, 0, stream>>>(ei, srcA, dstA);
    k_zero32<<<(NN + 255) / 256, 256, 0, stream>>>((unsigned int*)cnt, NN);
    k_count<<<ebB, 256, 0, stream>>>(dstA, cnt);
    k_scan<<<1, 256, 0, stream>>>(cnt, eoff, cur);
    k_fill<<<ebB, 256, 0, stream>>>(srcA, dstA, cur, slist);

    // layer-1 input -> fp16 (only conversion needed; later layers emit fp16)
    int nA = NN * 1536;
    k_cvtA<<<(nA + 255) / 256, 256, 0, stream>>>(x, a0p, nA);

    // three GATv2 layers
    run_gat_layer(a0p, 1536, 1024, Wl1, bl1, Wr1, br1, att1, b1,
                  wb0, xlr, eoff, slist, x1, stream);
    run_gat_layer(x1,  1024, 512,  Wl2, bl2, Wr2, br2, att2, b2,
                  wb0, xlr, eoff, slist, x2, stream);
    run_gat_layer(x2,  512,  256,  Wl3, bl3, Wr3, br3, att3, b3,
                  wb0, xlr, eoff, slist, x3, stream);

    // gate + pool + MLP
    k_gate<<<NN, 128, 0, stream>>>(x3, Wg0, bg0, Wg1, bg1, g);
    k_zero32<<<1, 64, 0, stream>>>((unsigned int*)gstart, 2 * NG);
    k_group_bounds<<<(NN + 255) / 256, 256, 0, stream>>>(batch, gstart, gend);
    k_pool_stats<<<NG, 256, 0, stream>>>(g, gstart, gend, gm, ginv);
    k_zero32<<<(NG * 256 + 255) / 256, 256, 0, stream>>>((unsigned int*)hpool, NG * 256);
    k_pool_acc<<<(NN + PCH - 1) / PCH, 256, 0, stream>>>(x3, g, batch, gm, ginv, hpool);
    k_mlp<<<1, 256, 0, stream>>>(hpool, Wm0, bm0, Wm1, bm1, Wm2, bm2,
                                 Wm3, bm3, Wm4, bm4, out);
}

// Round 4
// 668.243 us; speedup vs baseline: 1.1558x; 1.0410x over previous
//
#include <hip/hip_runtime.h>
#include <math.h>
#include <type_traits>

// Problem constants (from reference)
#define NN 5000
#define NNP 5120    // padded rows for GEMM A-operand OOB staging
#define NE 50000
#define NEE 55000   // edges + self loops
#define NG 8
#define NH 4

typedef __attribute__((ext_vector_type(8))) _Float16 half8;
typedef __attribute__((ext_vector_type(4))) _Float16 half4;
typedef __attribute__((ext_vector_type(4))) float floatx4;

// ---------------- utility device functions ----------------

__device__ inline float waveSum(float v) {
    #pragma unroll
    for (int o = 32; o > 0; o >>= 1) v += __shfl_xor(v, o, 64);
    return v;
}
__device__ inline float waveMax(float v) {
    #pragma unroll
    for (int o = 32; o > 0; o >>= 1) v = fmaxf(v, __shfl_xor(v, o, 64));
    return v;
}

// async global->LDS DMA, 16B per lane; lds dest is wave-uniform base + lane*16
__device__ __forceinline__ void gload_lds16(const _Float16* g, _Float16* l) {
    __builtin_amdgcn_global_load_lds(
        (__attribute__((address_space(1))) void*)g,
        (__attribute__((address_space(3))) void*)l,
        16, 0, 0);
}

template<int N>
__device__ __forceinline__ void vmgate() {
    if constexpr (N == 0) asm volatile("s_waitcnt vmcnt(0)" ::: "memory");
    else if constexpr (N == 2) asm volatile("s_waitcnt vmcnt(2)" ::: "memory");
    else if constexpr (N == 4) asm volatile("s_waitcnt vmcnt(4)" ::: "memory");
    // N < 0: no gate
}

// ---------------- fp32 -> fp16 conversion ----------------

__global__ void k_cvtA(const float* __restrict__ X, _Float16* __restrict__ A0, int n) {
    int i = blockIdx.x * 256 + threadIdx.x;
    if (i >= n) return;
    A0[i] = (_Float16)X[i];
}

// W (K x M fp32) -> B0 fp16 TRANSPOSED to (M x K)
__global__ __launch_bounds__(256) void k_cvtWT(const float* __restrict__ W,
        _Float16* __restrict__ B0, int K, int M)
{
    __shared__ float tile[32][33];
    int m0 = blockIdx.x * 32, k0 = blockIdx.y * 32;
    int tx = threadIdx.x & 31, ty = threadIdx.x >> 5;
    #pragma unroll
    for (int i = 0; i < 4; ++i)
        tile[ty + 8 * i][tx] = W[(size_t)(k0 + ty + 8 * i) * M + m0 + tx];
    __syncthreads();
    #pragma unroll
    for (int i = 0; i < 4; ++i) {
        int mm = ty + 8 * i, kk = tx;
        B0[(size_t)(m0 + mm) * K + kk + k0] = (_Float16)tile[kk][mm];
    }
}

// ============ 256x256 / BK=64 / 8-wave phase-split GEMM ====================
// R3 post-mortem: 4-phase loop measured 5670 cy/tile vs MFMA 2484 + LDS 1536.
// Causes: (a) frags re-read every phase (48 b128/tile/wave; no cross-phase
// register hold) -> LDS time doubled; (b) vmcnt slack ~0.5 tile < HBM latency.
// R4: phase order (0,0),(0,1),(1,0),(1,1); A-frags held across the QB pair,
// B-frags (bf0 ph1->ph3, bf1 ph2->ph4) held across the QA pair -> reads
// 24 b128/tile/wave (ph1:12, ph2:4, ph3:8, ph4:0) = 196KB/CU-tile = 768 cy.
// Staging unit issue order per tile t (for t+1): Ah0@ph1, Bh0@ph2, Bh1@ph3,
// Ah1@ph4; need order next tile: Ah0,Bh0 by ph1; Bh1 by ph2; Ah1 by ph3.
// Gates (outstanding-count verified, all vmcnt(4)): end-ph1 -> Bh1(t) landed;
// end-ph2 -> Ah1(t) landed; end-ph4 -> Ah0,Bh0(t+1) landed; ph3 no gate.
// Every unit gets >=2 phases (~1600cy) in flight >= ~900cy HBM latency.
// LDS chunk swizzle (both-sides, m173): global chunk (c^row&7), linear dest;
// reads XOR the same key -> conflict-free ds_read_b128.
__global__ __launch_bounds__(512, 2) void gemm256_mfma_f16(
    const _Float16* __restrict__ A0, const _Float16* __restrict__ B0,
    const float* __restrict__ biasL, const float* __restrict__ biasR,
    int Nhalf, _Float16* __restrict__ C,
    int Mrows, int K, int N)
{
    // [dbuf][ A 256*64 | B 256*64 ] halfs = 128 KB total
    __shared__ __align__(16) _Float16 smem[2 * 32768];

    const int tid  = threadIdx.x;
    const int wave = tid >> 6;
    const int lane = tid & 63;
    const int wr = wave >> 2;      // 0..1  (M half within a quadrant)
    const int wc = wave & 3;       // 0..3  (N quarter within a quadrant)
    const int rowBase = blockIdx.y * 256;
    const int colBase = blockIdx.x * 256;

    floatx4 acc[2][2][4][2];
    #pragma unroll
    for (int qa = 0; qa < 2; ++qa)
        #pragma unroll
        for (int qb = 0; qb < 2; ++qb)
            #pragma unroll
            for (int f = 0; f < 4; ++f)
                #pragma unroll
                for (int g = 0; g < 2; ++g)
                    acc[qa][qb][f][g] = (floatx4){0.f, 0.f, 0.f, 0.f};

    // staging: wave w stages rows h*128 + w*16 .. +16 (2 calls of 8 rows).
    // lane -> row lane>>3, global chunk (lane&7)^(lane>>3), linear LDS dest.
    const int srow   = lane >> 3;
    const int schunk = ((lane & 7) ^ srow) << 3;   // halfs
    const _Float16* gA = A0 + (size_t)(rowBase + wave * 16 + srow) * K + schunk;
    const _Float16* gB = B0 + (size_t)(colBase + wave * 16 + srow) * K + schunk;
    const size_t rstep = (size_t)8 * K;
    const size_t hstep = (size_t)128 * K;

    auto stageA = [&](int b, int h, int kt) {
        _Float16* l = &smem[b * 32768 + (h * 128 + wave * 16) * 64];
        const _Float16* g = gA + (size_t)h * hstep + (size_t)kt * 64;
        gload_lds16(g, l);
        gload_lds16(g + rstep, l + 512);
    };
    auto stageB = [&](int b, int h, int kt) {
        _Float16* l = &smem[b * 32768 + 16384 + (h * 128 + wave * 16) * 64];
        const _Float16* g = gB + (size_t)h * hstep + (size_t)kt * 64;
        gload_lds16(g, l);
        gload_lds16(g + rstep, l + 512);
    };

    const int lm  = lane & 15;
    const int key = lane & 7;
    const int kg  = lane >> 4;

    half8 af[4][2];        // A-frags for current QA (held across QB pair)
    half8 bf0[2][2];       // B-frags QB=0 (read ph1, reused ph3)
    half8 bf1[2][2];       // B-frags QB=1 (read ph2, reused ph4)

    auto readA = [&](const _Float16* Ab, int QA) {
        #pragma unroll
        for (int f = 0; f < 4; ++f)
            #pragma unroll
            for (int s = 0; s < 2; ++s) {
                int row = QA * 128 + wr * 64 + f * 16 + lm;
                int ch = (s * 4 + kg) ^ key;
                af[f][s] = *(const half8*)&Ab[row * 64 + ch * 8];
            }
    };
    auto readB = [&](const _Float16* Bb, int QB, half8 (&bf)[2][2]) {
        #pragma unroll
        for (int g = 0; g < 2; ++g)
            #pragma unroll
            for (int s = 0; s < 2; ++s) {
                int row = QB * 128 + wc * 32 + g * 16 + lm;
                int ch = (s * 4 + kg) ^ key;
                bf[g][s] = *(const half8*)&Bb[row * 64 + ch * 8];
            }
    };
    constexpr std::integral_constant<int, 0> I0{};
    constexpr std::integral_constant<int, 1> I1{};
    auto mfma16 = [&](auto QAc, auto QBc, half8 (&bf)[2][2]) {
        constexpr int QA = decltype(QAc)::value;
        constexpr int QB = decltype(QBc)::value;
        __builtin_amdgcn_s_setprio(1);
        #pragma unroll
        for (int f = 0; f < 4; ++f)
            #pragma unroll
            for (int g = 0; g < 2; ++g)
                #pragma unroll
                for (int s = 0; s < 2; ++s)
                    acc[QA][QB][f][g] = __builtin_amdgcn_mfma_f32_16x16x32_f16(
                        af[f][s], bf[g][s], acc[QA][QB][f][g], 0, 0, 0);
        __builtin_amdgcn_s_setprio(0);
    };

    // prologue: tile 0, issue order = steady-state age order Ah0,Bh0,Bh1,Ah1
    stageA(0, 0, 0); stageB(0, 0, 0); stageB(0, 1, 0); stageA(0, 1, 0);
    vmgate<4>();                      // Ah0,Bh0 landed
    __builtin_amdgcn_s_barrier();

    const int nk = K >> 6;
    for (int t = 0; t < nk - 1; ++t) {
        const int b = t & 1;
        const _Float16* Ab = &smem[b * 32768];
        const _Float16* Bb = Ab + 16384;
        // ph1 (0,0): reads A(QA0)+B(QB0); issue Ah0'; gate -> Bh1(t)
        readA(Ab, 0); readB(Bb, 0, bf0);
        stageA(b ^ 1, 0, t + 1);
        __builtin_amdgcn_s_barrier();
        mfma16(I0, I0, bf0);
        vmgate<4>();
        __builtin_amdgcn_s_barrier();
        __builtin_amdgcn_sched_barrier(0);
        // ph2 (0,1): reads B(QB1); A held; issue Bh0'; gate -> Ah1(t)
        readB(Bb, 1, bf1);
        stageB(b ^ 1, 0, t + 1);
        __builtin_amdgcn_s_barrier();
        mfma16(I0, I1, bf1);
        vmgate<4>();
        __builtin_amdgcn_s_barrier();
        __builtin_amdgcn_sched_barrier(0);
        // ph3 (1,0): reads A(QA1); B(QB0) held; issue Bh1'; no gate
        readA(Ab, 1);
        stageB(b ^ 1, 1, t + 1);
        __builtin_amdgcn_s_barrier();
        mfma16(I1, I0, bf0);
        __builtin_amdgcn_s_barrier();
        __builtin_amdgcn_sched_barrier(0);
        // ph4 (1,1): no reads; issue Ah1'; gate -> Ah0',Bh0' (t+1)
        stageA(b ^ 1, 1, t + 1);
        __builtin_amdgcn_s_barrier();
        mfma16(I1, I1, bf1);
        vmgate<4>();
        __builtin_amdgcn_s_barrier();
        __builtin_amdgcn_sched_barrier(0);
    }
    {   // last tile: no staging; outstanding at entry = {Bh1, Ah1} (4 loads)
        const int b = (nk - 1) & 1;
        const _Float16* Ab = &smem[b * 32768];
        const _Float16* Bb = Ab + 16384;
        readA(Ab, 0); readB(Bb, 0, bf0);
        __builtin_amdgcn_s_barrier();
        mfma16(I0, I0, bf0);
        vmgate<2>();                  // Bh1 landed
        __builtin_amdgcn_s_barrier();
        readB(Bb, 1, bf1);
        __builtin_amdgcn_s_barrier();
        mfma16(I0, I1, bf1);
        vmgate<0>();                  // Ah1 landed
        __builtin_amdgcn_s_barrier();
        readA(Ab, 1);
        __builtin_amdgcn_s_barrier();
        mfma16(I1, I0, bf0);
        __builtin_amdgcn_s_barrier();
        mfma16(I1, I1, bf1);
        __builtin_amdgcn_s_barrier();
    }

    // ---- coalesced epilogue: stage 256x256 C-tile in the dead LDS ----
    // 32B-granule XOR by (row>>2)&7: 4 lane-groups -> 4 distinct bank
    // quadrants; bijective per row.
    _Float16* Ct = smem;
    const int cq = (lane >> 4) * 4;
    #pragma unroll
    for (int qb = 0; qb < 2; ++qb)
        #pragma unroll
        for (int g = 0; g < 2; ++g) {
            int col = qb * 128 + wc * 32 + g * 16 + lm;
            int gcol = colBase + col;
            float bv = (gcol < Nhalf) ? biasL[gcol] : biasR[gcol - Nhalf];
            #pragma unroll
            for (int qa = 0; qa < 2; ++qa)
                #pragma unroll
                for (int f = 0; f < 4; ++f)
                    #pragma unroll
                    for (int r = 0; r < 4; ++r) {
                        int row = qa * 128 + wr * 64 + f * 16 + cq + r;
                        int gi = (col >> 4) ^ ((row >> 2) & 7);
                        Ct[row * 256 + gi * 16 + (col & 15)] =
                            (_Float16)(acc[qa][qb][f][g][r] + bv);
                    }
        }
    __syncthreads();
    // 512 threads store 16 rows/pass (row = 512B contiguous), 16 passes
    const int r0 = tid >> 5;           // 0..15
    const int cc = (tid & 31) * 8;     // halfs within row
    const int gg = cc >> 4;
    #pragma unroll
    for (int ps = 0; ps < 16; ++ps) {
        int row = ps * 16 + r0;
        int grow = rowBase + row;
        if (grow < Mrows) {
            int gp = gg ^ ((row >> 2) & 7);
            half8 v = *(const half8*)&Ct[row * 256 + gp * 16 + (cc & 15)];
            *(half8*)&C[(size_t)grow * N + colBase + cc] = v;
        }
    }
}

// ---------------- 128x128 MFMA GEMM (proven R2 kernel; layer-3) ------------
__global__ __launch_bounds__(256) void gemm_mfma_f16(
    const _Float16* __restrict__ A0, const _Float16* __restrict__ B0,
    const float* __restrict__ biasL, const float* __restrict__ biasR,
    int Nhalf, _Float16* __restrict__ C,
    int Mrows, int K, int N)
{
    __shared__ __align__(16) _Float16 smem[2 * 2 * 128 * 32];
    _Float16* As = smem;
    _Float16* Bs = smem + 2 * 128 * 32;

    const int tid = threadIdx.x;
    const int wave = tid >> 6;
    const int lane = tid & 63;
    const int wm = (wave >> 1) * 64;
    const int wn = (wave & 1) * 64;
    const int lm = lane & 15;
    const int swz = (((lane >> 4) ^ ((lane >> 1) & 3)) << 3);

    const int rowBase = blockIdx.y * 128;
    const int colBase = blockIdx.x * 128;

    floatx4 acc[4][4];
    #pragma unroll
    for (int i = 0; i < 4; ++i)
        #pragma unroll
        for (int j = 0; j < 4; ++j)
            acc[i][j] = (floatx4){0.f, 0.f, 0.f, 0.f};

    const int sr = lane >> 2;
    const int scol = (((lane & 3) ^ ((lane >> 3) & 3)) << 3);
    const _Float16* gA = A0 + (size_t)(rowBase + wave * 32 + sr) * K + scol;
    const _Float16* gB = B0 + (size_t)(colBase + wave * 32 + sr) * K + scol;
    const size_t skip16 = (size_t)16 * K;
    const int lo0 = (wave * 32) * 32;
    const int lo1 = (wave * 32 + 16) * 32;

    gload_lds16(gA, &As[lo0]);
    gload_lds16(gA + skip16, &As[lo1]);
    gload_lds16(gB, &Bs[lo0]);
    gload_lds16(gB + skip16, &Bs[lo1]);
    __syncthreads();

    const int nk = K >> 5;
    for (int t = 0; t < nk; ++t) {
        const int p = t & 1;
        const int po = p * 128 * 32;
        if (t + 1 < nk) {
            const int k1 = (t + 1) << 5;
            const int qo = (p ^ 1) * 128 * 32;
            gload_lds16(gA + k1, &As[qo + lo0]);
            gload_lds16(gA + skip16 + k1, &As[qo + lo1]);
            gload_lds16(gB + k1, &Bs[qo + lo0]);
            gload_lds16(gB + skip16 + k1, &Bs[qo + lo1]);
        }
        half8 a0[4], b0[4];
        #pragma unroll
        for (int i = 0; i < 4; ++i) {
            a0[i] = *(const half8*)&As[po + (wm + i * 16 + lm) * 32 + swz];
            b0[i] = *(const half8*)&Bs[po + (wn + i * 16 + lm) * 32 + swz];
        }
        #pragma unroll
        for (int i = 0; i < 4; ++i)
            #pragma unroll
            for (int j = 0; j < 4; ++j)
                acc[i][j] = __builtin_amdgcn_mfma_f32_16x16x32_f16(a0[i], b0[j], acc[i][j], 0, 0, 0);
        __syncthreads();
    }

    _Float16* Ct = smem;
    const int cq = (lane >> 4) * 4;
    #pragma unroll
    for (int j = 0; j < 4; ++j) {
        int col = wn + j * 16 + lm;
        int gcol = colBase + col;
        float bv = (gcol < Nhalf) ? biasL[gcol] : biasR[gcol - Nhalf];
        #pragma unroll
        for (int i = 0; i < 4; ++i) {
            int row = wm + i * 16 + cq;
            #pragma unroll
            for (int r = 0; r < 4; ++r) {
                int rr = row + r;
                Ct[rr * 128 + (col ^ (((rr >> 2) & 7) << 4))] = (_Float16)(acc[i][j][r] + bv);
            }
        }
    }
    __syncthreads();
    const int r0 = tid >> 4;
    const int cc = (tid & 15) * 8;
    #pragma unroll
    for (int ps = 0; ps < 8; ++ps) {
        int row = ps * 16 + r0;
        int grow = rowBase + row;
        if (grow < Mrows) {
            half8 v = *(const half8*)&Ct[row * 128 + (cc ^ (((row >> 2) & 7) << 4))];
            *(half8*)&C[(size_t)grow * N + colBase + cc] = v;
        }
    }
}

// ---------------- CSR build ----------------

__global__ void k_build_edges(const int* __restrict__ ei, int* __restrict__ src,
                              int* __restrict__ dst) {
    int i = blockIdx.x * 256 + threadIdx.x;
    if (i < NE) { src[i] = ei[i]; dst[i] = ei[NE + i]; }
    else if (i < NEE) { src[i] = i - NE; dst[i] = i - NE; }
}

__global__ void k_zero32(unsigned int* __restrict__ p, int n) {
    int i = blockIdx.x * 256 + threadIdx.x;
    if (i < n) p[i] = 0u;
}

__global__ void k_count(const int* __restrict__ dst, int* __restrict__ cnt) {
    int i = blockIdx.x * 256 + threadIdx.x;
    if (i < NEE) atomicAdd(&cnt[dst[i]], 1);
}

__global__ __launch_bounds__(256) void k_scan(const int* __restrict__ cnt,
                                              int* __restrict__ off, int* __restrict__ cur) {
    __shared__ int partial[256];
    __shared__ int ppre[257];
    int t = threadIdx.x;
    const int chunk = (NN + 255) / 256;
    int lo = t * chunk, hi = min(NN, (t + 1) * chunk);
    int s = 0;
    for (int i = lo; i < hi; ++i) s += cnt[i];
    partial[t] = s;
    __syncthreads();
    if (t == 0) {
        int acc = 0;
        for (int i = 0; i < 256; ++i) { ppre[i] = acc; acc += partial[i]; }
        ppre[256] = acc;
    }
    __syncthreads();
    int acc = ppre[t];
    for (int i = lo; i < hi; ++i) { off[i] = acc; cur[i] = acc; acc += cnt[i]; }
    if (t == 0) off[NN] = ppre[256];
}

__global__ void k_fill(const int* __restrict__ src, const int* __restrict__ dst,
                       int* __restrict__ cur, int* __restrict__ slist) {
    int e = blockIdx.x * 256 + threadIdx.x;
    if (e < NEE) { int p = atomicAdd(&cur[dst[e]], 1); slist[p] = src[e]; }
}

// ---------------- fused GATv2 edge pipeline (fp16 activations) -------------
template<int C>
__global__ __launch_bounds__(256) void k_gat_fused(
    const _Float16* __restrict__ xlr, const float* __restrict__ att,
    const int* __restrict__ eoff, const int* __restrict__ slist,
    const float* __restrict__ bias, _Float16* __restrict__ out)
{
    constexpr int LD = 2 * NH * C;          // fused GEMM row stride (halfs)
    constexpr int CH = (C >= 512) ? 8 : 4;  // halfs per load per lane
    constexpr int NC = C / (64 * CH);       // chunks per head-row
    constexpr int PL = NC * CH;             // elems per lane
    __shared__ float red[NH * C];
    const int n = blockIdx.x;
    const int h = threadIdx.x >> 6;
    const int lane = threadIdx.x & 63;

    float xrv[PL], attv[PL], acc[PL];
    {
        const _Float16* xrrow = xlr + (size_t)n * LD + NH * C + h * C + lane * CH;
        const float* ah = att + h * C + lane * CH;
        #pragma unroll
        for (int c = 0; c < NC; ++c) {
            if constexpr (CH == 8) {
                half8 hv = *(const half8*)(xrrow + c * 64 * CH);
                #pragma unroll
                for (int e = 0; e < 8; ++e) xrv[c * 8 + e] = (float)hv[e];
            } else {
                half4 hv = *(const half4*)(xrrow + c * 64 * CH);
                #pragma unroll
                for (int e = 0; e < 4; ++e) xrv[c * 4 + e] = (float)hv[e];
            }
            #pragma unroll
            for (int e = 0; e < CH; e += 4) {
                float4 a4 = *(const float4*)(ah + c * 64 * CH + e);
                attv[c * CH + e + 0] = a4.x; attv[c * CH + e + 1] = a4.y;
                attv[c * CH + e + 2] = a4.z; attv[c * CH + e + 3] = a4.w;
            }
        }
        #pragma unroll
        for (int e = 0; e < PL; ++e) acc[e] = 0.f;
    }

    float m = -INFINITY, den = 0.f;
    const int start = eoff[n], end = eoff[n + 1];

    _Float16 bufA[PL], bufB[PL];
    auto ldrow = [&](int s, _Float16* buf) {
        const _Float16* p = xlr + (size_t)s * LD + h * C + lane * CH;
        #pragma unroll
        for (int c = 0; c < NC; ++c) {
            if constexpr (CH == 8)
                *(half8*)&buf[c * 8] = *(const half8*)(p + c * 64 * CH);
            else
                *(half4*)&buf[c * 4] = *(const half4*)(p + c * 64 * CH);
        }
    };

    if (start < end) ldrow(slist[start], bufA);
    for (int j = start; j < end; ++j) {
        if (j + 1 < end) ldrow(slist[j + 1], bufB);   // prefetch next src row
        float xv[PL];
        float ps = 0.f;
        #pragma unroll
        for (int e = 0; e < PL; ++e) {
            xv[e] = (float)bufA[e];
            float v = xv[e] + xrv[e];
            v = v > 0.f ? v : 0.2f * v;
            ps = fmaf(v, attv[e], ps);
        }
        ps = waveSum(ps);
        float m_new = fmaxf(m, ps);
        float scale = expf(m - m_new);
        float ex = expf(ps - m_new);
        den = den * scale + ex;
        m = m_new;
        #pragma unroll
        for (int e = 0; e < PL; ++e)
            acc[e] = fmaf(ex, xv[e], acc[e] * scale);
        #pragma unroll
        for (int e = 0; e < PL; ++e) bufA[e] = bufB[e];
    }

    float inv = 1.f / (den + 1e-16f);
    #pragma unroll
    for (int c = 0; c < NC; ++c) {
        int off = h * C + c * 64 * CH + lane * CH;
        #pragma unroll
        for (int e = 0; e < CH; e += 4) {
            float4 r;
            r.x = acc[c * CH + e + 0] * inv;
            r.y = acc[c * CH + e + 1] * inv;
            r.z = acc[c * CH + e + 2] * inv;
            r.w = acc[c * CH + e + 3] * inv;
            *(float4*)&red[off + e] = r;
        }
    }
    __syncthreads();

    int t = threadIdx.x;
    for (int c4 = t; c4 < C / 4; c4 += 256) {
        int c = c4 * 4;
        float4 r0 = *(const float4*)&red[0 * C + c];
        float4 r1 = *(const float4*)&red[1 * C + c];
        float4 r2 = *(const float4*)&red[2 * C + c];
        float4 r3 = *(const float4*)&red[3 * C + c];
        float4 bv = *(const float4*)(bias + c);
        half4 o;
        o[0] = (_Float16)fmaxf((r0.x + r1.x + r2.x + r3.x) * 0.25f + bv.x, 0.f);
        o[1] = (_Float16)fmaxf((r0.y + r1.y + r2.y + r3.y) * 0.25f + bv.y, 0.f);
        o[2] = (_Float16)fmaxf((r0.z + r1.z + r2.z + r3.z) * 0.25f + bv.z, 0.f);
        o[3] = (_Float16)fmaxf((r0.w + r1.w + r2.w + r3.w) * 0.25f + bv.w, 0.f);
        *(half4*)(out + (size_t)n * C + c) = o;
    }
}

// ---------------- gate + pool + MLP ----------------

__global__ __launch_bounds__(128) void k_gate(
    const _Float16* __restrict__ x, const float* __restrict__ Wg0,
    const float* __restrict__ bg0, const float* __restrict__ Wg1,
    const float* __restrict__ bg1, float* __restrict__ g)
{
    int n = blockIdx.x;
    int t = threadIdx.x;
    __shared__ float xs[256];
    __shared__ float wsum[2];
    const _Float16* xp = x + (size_t)n * 256;
    xs[t] = (float)xp[t]; xs[t + 128] = (float)xp[t + 128];
    __syncthreads();
    float acc = bg0[t];
    for (int k = 0; k < 256; ++k) acc = fmaf(xs[k], Wg0[k * 128 + t], acc);
    acc = acc > 0.f ? acc : 0.f;
    float prod = acc * Wg1[t];
    prod = waveSum(prod);
    if ((t & 63) == 0) wsum[t >> 6] = prod;
    __syncthreads();
    if (t == 0) g[n] = wsum[0] + wsum[1] + bg1[0];
}

__global__ void k_group_bounds(const int* __restrict__ batch, int* __restrict__ gstart,
                               int* __restrict__ gend) {
    int n = blockIdx.x * 256 + threadIdx.x;
    if (n >= NN) return;
    int b = batch[n];
    if (n == 0 || batch[n - 1] != b) gstart[b] = n;
    if (n == NN - 1 || batch[n + 1] != b) gend[b] = n + 1;
}

// per-group softmax stats: m[g], invden[g]
__global__ __launch_bounds__(256) void k_pool_stats(
    const float* __restrict__ g, const int* __restrict__ gstart,
    const int* __restrict__ gend, float* __restrict__ mOut,
    float* __restrict__ invdenOut)
{
    int gi = blockIdx.x;
    int t = threadIdx.x;
    int s0 = gstart[gi], e0 = gend[gi];
    __shared__ float red[4];
    float mx = -1e30f;
    for (int n = s0 + t; n < e0; n += 256) mx = fmaxf(mx, g[n]);
    float wm = waveMax(mx);
    if ((t & 63) == 0) red[t >> 6] = wm;
    __syncthreads();
    float m = fmaxf(fmaxf(red[0], red[1]), fmaxf(red[2], red[3]));
    __syncthreads();
    float sm = 0.f;
    for (int n = s0 + t; n < e0; n += 256) sm += expf(g[n] - m);
    sm = waveSum(sm);
    if ((t & 63) == 0) red[t >> 6] = sm;
    __syncthreads();
    if (t == 0) {
        float den = red[0] + red[1] + red[2] + red[3] + 1e-16f;
        mOut[gi] = m;
        invdenOut[gi] = 1.f / den;
    }
}

#define PCH 16
__global__ __launch_bounds__(256) void k_pool_acc(
    const _Float16* __restrict__ x, const float* __restrict__ g,
    const int* __restrict__ batch, const float* __restrict__ m,
    const float* __restrict__ invden, float* __restrict__ hpool)
{
    int base = blockIdx.x * PCH;
    int t = threadIdx.x;
    float acc = 0.f;
    int cur = -1;
    for (int i = 0; i < PCH; ++i) {
        int n = base + i;
        if (n >= NN) break;
        int b = batch[n];
        if (b != cur) {
            if (cur >= 0) atomicAdd(&hpool[cur * 256 + t], acc);
            cur = b; acc = 0.f;
        }
        float w = expf(g[n] - m[b]) * invden[b];
        acc = fmaf(w, (float)x[(size_t)n * 256 + t], acc);
    }
    if (cur >= 0) atomicAdd(&hpool[cur * 256 + t], acc);
}

__global__ __launch_bounds__(256) void k_mlp(
    const float* __restrict__ hpool,
    const float* __restrict__ Wm0, const float* __restrict__ bm0,
    const float* __restrict__ Wm1, const float* __restrict__ bm1,
    const float* __restrict__ Wm2, const float* __restrict__ bm2,
    const float* __restrict__ Wm3, const float* __restrict__ bm3,
    const float* __restrict__ Wm4, const float* __restrict__ bm4,
    float* __restrict__ out)
{
    __shared__ float bufA[8 * 256];
    __shared__ float bufB[8 * 128];
    int t = threadIdx.x;
    for (int i = t; i < 8 * 256; i += 256) bufA[i] = hpool[i];
    __syncthreads();
    for (int i = t; i < 8 * 128; i += 256) {
        int r = i >> 7, c = i & 127;
        float acc = bm0[c];
        for (int k = 0; k < 256; ++k) acc = fmaf(bufA[r * 256 + k], Wm0[k * 128 + c], acc);
        bufB[i] = fmaxf(acc, 0.f);
    }
    __syncthreads();
    for (int i = t; i < 8 * 64; i += 256) {
        int r = i >> 6, c = i & 63;
        float acc = bm1[c];
        for (int k = 0; k < 128; ++k) acc = fmaf(bufB[r * 128 + k], Wm1[k * 64 + c], acc);
        bufA[i] = fmaxf(acc, 0.f);
    }
    __syncthreads();
    for (int i = t; i < 8 * 32; i += 256) {
        int r = i >> 5, c = i & 31;
        float acc = bm2[c];
        for (int k = 0; k < 64; ++k) acc = fmaf(bufA[r * 64 + k], Wm2[k * 32 + c], acc);
        bufB[i] = fmaxf(acc, 0.f);
    }
    __syncthreads();
    for (int i = t; i < 8 * 16; i += 256) {
        int r = i >> 4, c = i & 15;
        float acc = bm3[c];
        for (int k = 0; k < 32; ++k) acc = fmaf(bufB[r * 32 + k], Wm3[k * 16 + c], acc);
        bufA[i] = fmaxf(acc, 0.f);
    }
    __syncthreads();
    if (t < 8) {
        float acc = bm4[0];
        for (int k = 0; k < 16; ++k) acc = fmaf(bufA[t * 16 + k], Wm4[k], acc);
        out[t] = acc;
    }
}

// ---------------- host orchestration ----------------

static void run_gat_layer(const _Float16* ain, int K, int C,
                          const float* Wl, const float* bl,
                          const float* Wr, const float* br,
                          const float* att, const float* bias,
                          _Float16* wb0, _Float16* xlr,
                          const int* eoff, const int* slist,
                          _Float16* xout, hipStream_t stream)
{
    int HC = NH * C;
    dim3 tgrid(HC / 32, K / 32);
    k_cvtWT<<<tgrid, 256, 0, stream>>>(Wl, wb0, K, HC);
    k_cvtWT<<<tgrid, 256, 0, stream>>>(Wr, wb0 + (size_t)HC * K, K, HC);
    // fused Wl/Wr GEMM: N = 2*HC, output row n = [xl(n) | xr(n)]
    if (C >= 512) {
        dim3 ggrid(2 * HC / 256, NNP / 256);
        gemm256_mfma_f16<<<ggrid, 512, 0, stream>>>(ain, wb0, bl, br, HC, xlr, NN, K, 2 * HC);
    } else {
        dim3 ggrid(2 * HC / 128, NNP / 128);
        gemm_mfma_f16<<<ggrid, 256, 0, stream>>>(ain, wb0, bl, br, HC, xlr, NN, K, 2 * HC);
    }

    if (C == 1024)
        k_gat_fused<1024><<<NN, 256, 0, stream>>>(xlr, att, eoff, slist, bias, xout);
    else if (C == 512)
        k_gat_fused<512><<<NN, 256, 0, stream>>>(xlr, att, eoff, slist, bias, xout);
    else
        k_gat_fused<256><<<NN, 256, 0, stream>>>(xlr, att, eoff, slist, bias, xout);
}

extern "C" void kernel_launch(void* const* d_in, const int* in_sizes, int n_in,
                              void* d_out, int out_size, void* d_ws, size_t ws_size,
                              hipStream_t stream) {
    const float* x      = (const float*)d_in[0];
    const int* ei       = (const int*)d_in[1];
    const int* batch    = (const int*)d_in[2];
    const float* Wl1 = (const float*)d_in[3];  const float* bl1 = (const float*)d_in[4];
    const float* Wr1 = (const float*)d_in[5];  const float* br1 = (const float*)d_in[6];
    const float* att1= (const float*)d_in[7];  const float* b1  = (const float*)d_in[8];
    const float* Wl2 = (const float*)d_in[9];  const float* bl2 = (const float*)d_in[10];
    const float* Wr2 = (const float*)d_in[11]; const float* br2 = (const float*)d_in[12];
    const float* att2= (const float*)d_in[13]; const float* b2  = (const float*)d_in[14];
    const float* Wl3 = (const float*)d_in[15]; const float* bl3 = (const float*)d_in[16];
    const float* Wr3 = (const float*)d_in[17]; const float* br3 = (const float*)d_in[18];
    const float* att3= (const float*)d_in[19]; const float* b3  = (const float*)d_in[20];
    const float* Wm0 = (const float*)d_in[21]; const float* bm0 = (const float*)d_in[22];
    const float* Wm1 = (const float*)d_in[23]; const float* bm1 = (const float*)d_in[24];
    const float* Wm2 = (const float*)d_in[25]; const float* bm2 = (const float*)d_in[26];
    const float* Wm3 = (const float*)d_in[27]; const float* bm3 = (const float*)d_in[28];
    const float* Wm4 = (const float*)d_in[29]; const float* bm4 = (const float*)d_in[30];
    const float* Wg0 = (const float*)d_in[31]; const float* bg0 = (const float*)d_in[32];
    const float* Wg1 = (const float*)d_in[33]; const float* bg1 = (const float*)d_in[34];
    float* out = (float*)d_out;

    // workspace carve (float units = 4B); fp16 buffers 16B-aligned, padded rows
    float* ws = (float*)d_ws;
    size_t o = 0;
    _Float16* xlr = (_Float16*)(ws + o); o += (size_t)NNP * 8192 / 2;  // fused [xl|xr], layer1 sized
    _Float16* x1  = (_Float16*)(ws + o); o += (size_t)NNP * 1024 / 2;
    _Float16* x2  = (_Float16*)(ws + o); o += (size_t)NNP * 512 / 2;
    _Float16* x3  = (_Float16*)(ws + o); o += (size_t)NNP * 256 / 2;
    _Float16* a0p = (_Float16*)(ws + o); o += (size_t)NNP * 1536 / 2;
    _Float16* wb0 = (_Float16*)(ws + o); o += (size_t)8192 * 1536 / 2; // [WlT | WrT], layer1 sized
    int* srcA    = (int*)(ws + o); o += NEE;
    int* dstA    = (int*)(ws + o); o += NEE;
    int* cnt     = (int*)(ws + o); o += NN;
    int* eoff    = (int*)(ws + o); o += NN + 1;
    int* cur     = (int*)(ws + o); o += NN;
    int* slist   = (int*)(ws + o); o += NEE;
    float* g     = ws + o; o += NN;
    int* gstart  = (int*)(ws + o); o += NG;
    int* gend    = (int*)(ws + o); o += NG;
    float* gm    = ws + o; o += NG;
    float* ginv  = ws + o; o += NG;
    float* hpool = ws + o; o += NG * 256;

    // build CSR by dst (slist holds src node ids)
    int ebB = (NEE + 255) / 256;
    k_build_edges<<<ebB, 256, 0, stream>>>(ei, srcA, dstA);
    k_zero32<<<(NN + 255) / 256, 256, 0, stream>>>((unsigned int*)cnt, NN);
    k_count<<<ebB, 256, 0, stream>>>(dstA, cnt);
    k_scan<<<1, 256, 0, stream>>>(cnt, eoff, cur);
    k_fill<<<ebB, 256, 0, stream>>>(srcA, dstA, cur, slist);

    // layer-1 input -> fp16 (only conversion needed; later layers emit fp16)
    int nA = NN * 1536;
    k_cvtA<<<(nA + 255) / 256, 256, 0, stream>>>(x, a0p, nA);

    // three GATv2 layers
    run_gat_layer(a0p, 1536, 1024, Wl1, bl1, Wr1, br1, att1, b1,
                  wb0, xlr, eoff, slist, x1, stream);
    run_gat_layer(x1,  1024, 512,  Wl2, bl2, Wr2, br2, att2, b2,
                  wb0, xlr, eoff, slist, x2, stream);
    run_gat_layer(x2,  512,  256,  Wl3, bl3, Wr3, br3, att3, b3,
                  wb0, xlr, eoff, slist, x3, stream);

    // gate + pool + MLP
    k_gate<<<NN, 128, 0, stream>>>(x3, Wg0, bg0, Wg1, bg1, g);
    k_zero32<<<1, 64, 0, stream>>>((unsigned int*)gstart, 2 * NG);
    k_group_bounds<<<(NN + 255) / 256, 256, 0, stream>>>(batch, gstart, gend);
    k_pool_stats<<<NG, 256, 0, stream>>>(g, gstart, gend, gm, ginv);
    k_zero32<<<(NG * 256 + 255) / 256, 256, 0, stream>>>((unsigned int*)hpool, NG * 256);
    k_pool_acc<<<(NN + PCH - 1) / PCH, 256, 0, stream>>>(x3, g, batch, gm, ginv, hpool);
    k_mlp<<<1, 256, 0, stream>>>(hpool, Wm0, bm0, Wm1, bm1, Wm2, bm2,
                                 Wm3, bm3, Wm4, bm4, out);
}